// Round 2
// baseline (4351.181 us; speedup 1.0000x reference)
//
#include <hip/hip_runtime.h>
#include <stdint.h>

#define NTOK 9600
#define TT   300
#define DD   1024
#define HH   8
#define DFF  4096
#define FIN  1152
#define DATT 128
#define NCLS 3862
#define TP   320   // kv padded for PV k-steps
#define NQT  19    // ceil(304/16) tiles of 16

typedef unsigned short u16;
typedef __attribute__((ext_vector_type(8))) short short8;
typedef __attribute__((ext_vector_type(4))) float f32x4;

__device__ __forceinline__ int imin(int a, int b){ return a < b ? a : b; }

__device__ __forceinline__ u16 f2bf(float f){
    union { float f; uint32_t u; } v; v.f = f;
    uint32_t u = v.u;
    return (u16)((u + 0x7fffu + ((u >> 16) & 1u)) >> 16);
}

__device__ __forceinline__ f32x4 mfma16(short8 a, short8 b, f32x4 c){
    return __builtin_amdgcn_mfma_f32_16x16x32_bf16(a, b, c, 0, 0, 0);
}

// ---------------- PE table ----------------
__global__ void __launch_bounds__(256) pe_kernel(float* __restrict__ pe)
{
    const int i = blockIdx.x * 256 + threadIdx.x;
    if (i >= TT * DD) return;
    const int t = i >> 10, d = i & 1023;
    const float fr = expf(-(float)(d & ~1) * (9.210340371976184f / 1024.0f));
    const float ang = (float)t * fr;
    pe[i] = (d & 1) ? cosf(ang) : sinf(ang);
}

// ---------------- feats concat + /255 -> bf16 ----------------
__global__ void __launch_bounds__(256) feats_kernel(const float* __restrict__ rgb,
        const float* __restrict__ aud, u16* __restrict__ out)
{
    const long i = (long)blockIdx.x * 256 + threadIdx.x;
    if (i >= (long)NTOK * FIN) return;
    const int row = (int)(i / FIN), c = (int)(i % FIN);
    const float v = (c < 1024) ? rgb[(size_t)row * 1024 + c] : aud[(size_t)row * 128 + (c - 1024)];
    out[i] = f2bf(v * (1.0f / 255.0f));
}

// ---------------- weight transpose + convert: W[K,N] f32 -> Wt[N,K] bf16 ----------------
__global__ void __launch_bounds__(256) wconv_kernel(const float* __restrict__ W,
        u16* __restrict__ Wt, int K, int N)
{
    __shared__ float tile[32][33];
    const int k0 = blockIdx.y * 32, n0 = blockIdx.x * 32;
    const int tx = threadIdx.x, ty = threadIdx.y;   // 32 x 8
    #pragma unroll
    for (int i = 0; i < 4; ++i) {
        const int k = k0 + ty + i * 8, n = n0 + tx;
        tile[ty + i * 8][tx] = (k < K && n < N) ? W[(size_t)k * N + n] : 0.f;
    }
    __syncthreads();
    #pragma unroll
    for (int i = 0; i < 4; ++i) {
        const int n = n0 + ty + i * 8, k = k0 + tx;
        if (n < N && k < K) Wt[(size_t)n * K + k] = f2bf(tile[tx][ty + i * 8]);
    }
}

// ---------------- f32 -> bf16 ----------------
__global__ void __launch_bounds__(256) f2bf_kernel(const float* __restrict__ in,
        u16* __restrict__ out, int n)
{
    const int i = blockIdx.x * 256 + threadIdx.x;
    if (i < n) out[i] = f2bf(in[i]);
}

// ---------------- LayerNorm (ddof=1, a*(x-m)/(std+eps)+b) ----------------
template<int WF>
__global__ void __launch_bounds__(256) ln_kernel(const float* __restrict__ xin,
        const float* __restrict__ ga, const float* __restrict__ gb,
        u16* __restrict__ ob, float* of)
{
    const int row = blockIdx.x, t = threadIdx.x;
    const float4 xv = *(const float4*)(xin + (size_t)row * 1024 + t * 4);
    float s1 = xv.x + xv.y + xv.z + xv.w;
    float s2 = xv.x * xv.x + xv.y * xv.y + xv.z * xv.z + xv.w * xv.w;
    #pragma unroll
    for (int o = 1; o < 64; o <<= 1) { s1 += __shfl_xor(s1, o); s2 += __shfl_xor(s2, o); }
    __shared__ float r1[4], r2[4];
    const int lane = t & 63, wid = t >> 6;
    if (lane == 0) { r1[wid] = s1; r2[wid] = s2; }
    __syncthreads();
    s1 = r1[0] + r1[1] + r1[2] + r1[3];
    s2 = r2[0] + r2[1] + r2[2] + r2[3];
    const float mean = s1 * (1.0f / 1024.0f);
    const float var  = (s2 - 1024.0f * mean * mean) * (1.0f / 1023.0f);
    const float inv  = 1.0f / (sqrtf(fmaxf(var, 0.f)) + 1e-6f);
    const float4 av  = *(const float4*)(ga + t * 4);
    const float4 bv  = *(const float4*)(gb + t * 4);
    const float y0 = av.x * (xv.x - mean) * inv + bv.x;
    const float y1 = av.y * (xv.y - mean) * inv + bv.y;
    const float y2 = av.z * (xv.z - mean) * inv + bv.z;
    const float y3 = av.w * (xv.w - mean) * inv + bv.w;
    ushort4 o4; o4.x = f2bf(y0); o4.y = f2bf(y1); o4.z = f2bf(y2); o4.w = f2bf(y3);
    *(ushort4*)(ob + (size_t)row * 1024 + t * 4) = o4;
    if (WF) {
        float4 yo; yo.x = y0; yo.y = y1; yo.z = y2; yo.w = y3;
        *(float4*)(of + (size_t)row * 1024 + t * 4) = yo;
    }
}

// ---------------- epilogue codes ----------------
#define EPI_EMBED        0
#define EPI_B_BF16       1
#define EPI_B_RELU_BF16  2
#define EPI_B_RES_F32    3
#define EPI_B_TANH_F32   4
#define EPI_B_TANH_BF16  5
#define EPI_B_F32        6

// ---------------- generic bf16 MFMA GEMM: C = A[M,K] * Bt[N,K]^T ----------------
template<int EPI>
__global__ void __launch_bounds__(256) gemm_k(const u16* __restrict__ A, const u16* __restrict__ Bt,
        const float* __restrict__ bias, const float* extra,
        float* outF, u16* outB, int M, int N, int K)
{
    __shared__ __align__(16) u16 As[4096];
    __shared__ __align__(16) u16 Bs[4096];
    const int tid = threadIdx.x;
    const int bm = blockIdx.y, bn = blockIdx.x;
    const int lane = tid & 63, wid = tid >> 6;
    const int lg = lane >> 4, lr = lane & 15;
    const int wr = wid >> 1, wc = wid & 1;

    const int srow = tid >> 2;
    const int skc  = (tid & 3) * 8;
    const size_t aoff0 = (size_t)imin(bm * 128 + srow,      M - 1) * K + skc;
    const size_t aoff1 = (size_t)imin(bm * 128 + srow + 64, M - 1) * K + skc;
    const size_t boff0 = (size_t)imin(bn * 128 + srow,      N - 1) * K + skc;
    const size_t boff1 = (size_t)imin(bn * 128 + srow + 64, N - 1) * K + skc;

    f32x4 acc[4][4] = {};

    for (int k0 = 0; k0 < K; k0 += 32) {
        const short8 va0 = *(const short8*)(A  + aoff0 + k0);
        const short8 va1 = *(const short8*)(A  + aoff1 + k0);
        const short8 vb0 = *(const short8*)(Bt + boff0 + k0);
        const short8 vb1 = *(const short8*)(Bt + boff1 + k0);
        __syncthreads();
        *(short8*)(As + tid * 8)        = va0;
        *(short8*)(As + 2048 + tid * 8) = va1;
        *(short8*)(Bs + tid * 8)        = vb0;
        *(short8*)(Bs + 2048 + tid * 8) = vb1;
        __syncthreads();
        short8 af[4], bf[4];
        #pragma unroll
        for (int m = 0; m < 4; ++m)
            af[m] = *(const short8*)(As + (wr * 64 + m * 16 + lr) * 32 + lg * 8);
        #pragma unroll
        for (int n = 0; n < 4; ++n)
            bf[n] = *(const short8*)(Bs + (wc * 64 + n * 16 + lr) * 32 + lg * 8);
        #pragma unroll
        for (int m = 0; m < 4; ++m)
            #pragma unroll
            for (int n = 0; n < 4; ++n)
                acc[m][n] = mfma16(af[m], bf[n], acc[m][n]);
    }

    #pragma unroll
    for (int m = 0; m < 4; ++m) {
        const int rb = bm * 128 + wr * 64 + m * 16 + lg * 4;
        #pragma unroll
        for (int n = 0; n < 4; ++n) {
            const int col = bn * 128 + wc * 64 + n * 16 + lr;
            if (col >= N) continue;
            const float bvl = bias[col];
            #pragma unroll
            for (int j = 0; j < 4; ++j) {
                const int r = rb + j;
                if (r >= M) continue;
                const float v = acc[m][n][j];
                const size_t oi = (size_t)r * N + col;
                if      (EPI == EPI_EMBED)       outF[oi] = (v + bvl) * 32.0f + extra[(size_t)(r % 300) * 1024 + col];
                else if (EPI == EPI_B_BF16)      outB[oi] = f2bf(v + bvl);
                else if (EPI == EPI_B_RELU_BF16) outB[oi] = f2bf(fmaxf(v + bvl, 0.f));
                else if (EPI == EPI_B_RES_F32)   outF[oi] = v + bvl + extra[oi];
                else if (EPI == EPI_B_TANH_F32)  outF[oi] = tanhf(v + bvl);
                else if (EPI == EPI_B_TANH_BF16) outB[oi] = f2bf(tanhf(v + bvl));
                else                             outF[oi] = v + bvl;
            }
        }
    }
}

// ---------------- GEMM with on-the-fly B transpose: C = A[M,K]bf16 * B[K,N]f32 ----------------
template<int EPI>
__global__ void __launch_bounds__(256) gemm_nt(const u16* __restrict__ A, const float* __restrict__ B,
        const float* __restrict__ bias, float* outF, u16* outB, int M, int N, int K)
{
    __shared__ __align__(16) u16 As[4096];
    __shared__ __align__(16) u16 Bs[4096];
    const int tid = threadIdx.x;
    const int bm = blockIdx.y, bn = blockIdx.x;
    const int lane = tid & 63, wid = tid >> 6;
    const int lg = lane >> 4, lr = lane & 15;
    const int wr = wid >> 1, wc = wid & 1;

    const int srow = tid >> 2;
    const int skc  = (tid & 3) * 8;
    const size_t aoff0 = (size_t)imin(bm * 128 + srow,      M - 1) * K + skc;
    const size_t aoff1 = (size_t)imin(bm * 128 + srow + 64, M - 1) * K + skc;
    const int bkr = tid >> 3;          // 0..31 : k within tile
    const int bnc = (tid & 7) * 16;    // col group of 16

    f32x4 acc[4][4] = {};

    for (int k0 = 0; k0 < K; k0 += 32) {
        const short8 va0 = *(const short8*)(A + aoff0 + k0);
        const short8 va1 = *(const short8*)(A + aoff1 + k0);
        float wv[16];
        #pragma unroll
        for (int j = 0; j < 16; ++j)
            wv[j] = B[(size_t)(k0 + bkr) * N + imin(bn * 128 + bnc + j, N - 1)];
        __syncthreads();
        *(short8*)(As + tid * 8)        = va0;
        *(short8*)(As + 2048 + tid * 8) = va1;
        #pragma unroll
        for (int j = 0; j < 16; ++j)
            Bs[(bnc + j) * 32 + bkr] = f2bf(wv[j]);
        __syncthreads();
        short8 af[4], bf[4];
        #pragma unroll
        for (int m = 0; m < 4; ++m)
            af[m] = *(const short8*)(As + (wr * 64 + m * 16 + lr) * 32 + lg * 8);
        #pragma unroll
        for (int n = 0; n < 4; ++n)
            bf[n] = *(const short8*)(Bs + (wc * 64 + n * 16 + lr) * 32 + lg * 8);
        #pragma unroll
        for (int m = 0; m < 4; ++m)
            #pragma unroll
            for (int n = 0; n < 4; ++n)
                acc[m][n] = mfma16(af[m], bf[n], acc[m][n]);
    }

    #pragma unroll
    for (int m = 0; m < 4; ++m) {
        const int rb = bm * 128 + wr * 64 + m * 16 + lg * 4;
        #pragma unroll
        for (int n = 0; n < 4; ++n) {
            const int col = bn * 128 + wc * 64 + n * 16 + lr;
            if (col >= N) continue;
            const float bvl = bias[col];
            #pragma unroll
            for (int j = 0; j < 4; ++j) {
                const int r = rb + j;
                if (r >= M) continue;
                const float v = acc[m][n][j];
                const size_t oi = (size_t)r * N + col;
                if      (EPI == EPI_B_TANH_BF16) outB[oi] = f2bf(tanhf(v + bvl));
                else                             outF[oi] = v + bvl;
            }
        }
    }
}

// ---------------- attention: scores + softmax -> P bf16 (chunk of bh) ----------------
__global__ void __launch_bounds__(256) attn_scores_kernel(const u16* __restrict__ Qb,
        const u16* __restrict__ Kb, u16* __restrict__ P, int bh0)
{
    __shared__ __align__(16) u16 Ks[304 * 128];   // 77824 B, XOR-swizzled rows
    const int bh = bh0 + blockIdx.x, b = bh >> 3, h = bh & 7;
    const int tid = threadIdx.x, lane = tid & 63, wid = tid >> 6;
    const int lg = lane >> 4, lr = lane & 15;

    for (int c = tid; c < 304 * 16; c += 256) {
        const int kv = c >> 4, part = c & 15;
        const int tok = b * 300 + imin(kv, 299);
        const short8 v = *(const short8*)(Kb + (size_t)tok * 1024 + h * 128 + part * 8);
        int byte_ = kv * 256 + part * 16;
        byte_ ^= (kv & 7) << 4;
        *(short8*)((char*)Ks + byte_) = v;
    }
    __syncthreads();

    const float scale = 0.08838834764831845f;   // 1/sqrt(128)
    for (int qt = wid; qt < NQT; qt += 4) {
        f32x4 acc[NQT] = {};
        const int qtok = b * 300 + imin(qt * 16 + lr, 299);
        const u16* qrow = Qb + (size_t)qtok * 1024 + h * 128;
        #pragma unroll
        for (int kk = 0; kk < 4; ++kk) {
            const short8 aq = *(const short8*)(qrow + kk * 32 + lg * 8);
            #pragma unroll
            for (int nt = 0; nt < NQT; ++nt) {
                const int kvrow = nt * 16 + lr;
                int byte_ = kvrow * 256 + kk * 64 + lg * 16;
                byte_ ^= (kvrow & 7) << 4;
                const short8 bk = *(const short8*)((char*)Ks + byte_);
                acc[nt] = mfma16(aq, bk, acc[nt]);
            }
        }
        #pragma unroll
        for (int j = 0; j < 4; ++j) {
            float vals[NQT];
            float m = -1e30f;
            #pragma unroll
            for (int nt = 0; nt < NQT; ++nt) {
                float s = acc[nt][j] * scale;
                if (nt * 16 + lr >= 300) s = -1e30f;
                vals[nt] = s;
                m = fmaxf(m, s);
            }
            #pragma unroll
            for (int o = 1; o < 16; o <<= 1) m = fmaxf(m, __shfl_xor(m, o));
            float sum = 0.f;
            #pragma unroll
            for (int nt = 0; nt < NQT; ++nt) { const float e = __expf(vals[nt] - m); vals[nt] = e; sum += e; }
            #pragma unroll
            for (int o = 1; o < 16; o <<= 1) sum += __shfl_xor(sum, o);
            const float inv = 1.0f / sum;
            const int q = qt * 16 + lg * 4 + j;
            if (q < 300) {
                u16* prow = P + ((size_t)blockIdx.x * 300 + q) * TP;
                #pragma unroll
                for (int nt = 0; nt < NQT; ++nt) prow[nt * 16 + lr] = f2bf(vals[nt] * inv);
                prow[304 + lr] = 0;   // zero kv pad 304..319
            }
        }
    }
}

// ---------------- attention: O = P @ V (chunk of bh) ----------------
__global__ void __launch_bounds__(256) attn_pv_kernel(const u16* __restrict__ P,
        const u16* __restrict__ Vb, u16* __restrict__ O, int bh0)
{
    __shared__ __align__(16) u16 Vs[128 * TP];   // V^T, 81920 B, XOR-swizzled rows
    const int bh = bh0 + blockIdx.x, b = bh >> 3, h = bh & 7;
    const int tid = threadIdx.x, lane = tid & 63, wid = tid >> 6;
    const int lg = lane >> 4, lr = lane & 15;

    for (int c = tid; c < 304 * 16; c += 256) {
        const int kv = c >> 4, dp = c & 15;
        const int tok = b * 300 + imin(kv, 299);
        const short8 v = *(const short8*)(Vb + (size_t)tok * 1024 + h * 128 + dp * 8);
        #pragma unroll
        for (int jj = 0; jj < 8; ++jj) {
            const int d = dp * 8 + jj;
            int byte_ = d * (TP * 2) + kv * 2;
            byte_ ^= (d & 7) << 4;
            *(u16*)((char*)Vs + byte_) = (u16)v[jj];
        }
    }
    for (int c = tid; c < 128 * 16; c += 256) {     // zero kv pad 304..319
        const int d = c >> 4, kv = 304 + (c & 15);
        int byte_ = d * (TP * 2) + kv * 2;
        byte_ ^= (d & 7) << 4;
        *(u16*)((char*)Vs + byte_) = 0;
    }
    __syncthreads();

    for (int qt = wid; qt < NQT; qt += 4) {
        f32x4 acc[8] = {};
        const int q = imin(qt * 16 + lr, 299);
        const u16* prow = P + ((size_t)blockIdx.x * 300 + q) * TP;
        #pragma unroll
        for (int kk = 0; kk < 10; ++kk) {
            const short8 ap = *(const short8*)(prow + kk * 32 + lg * 8);
            #pragma unroll
            for (int nt = 0; nt < 8; ++nt) {
                const int d = nt * 16 + lr;
                int byte_ = d * (TP * 2) + kk * 64 + lg * 16;
                byte_ ^= (d & 7) << 4;
                const short8 bv8 = *(const short8*)((char*)Vs + byte_);
                acc[nt] = mfma16(ap, bv8, acc[nt]);
            }
        }
        #pragma unroll
        for (int nt = 0; nt < 8; ++nt) {
            #pragma unroll
            for (int j = 0; j < 4; ++j) {
                const int qq = qt * 16 + lg * 4 + j;
                if (qq < 300)
                    O[((size_t)(b * 300 + qq)) * 1024 + h * 128 + nt * 16 + lr] = f2bf(acc[nt][j]);
            }
        }
    }
}

// ---------------- classifier tail ----------------
__global__ void __launch_bounds__(256) logits_kernel(const float* __restrict__ a1,
        const float* __restrict__ cw2, const float* __restrict__ cb2, float* __restrict__ out)
{
    const int tok = blockIdx.x * 4 + (threadIdx.x >> 6);
    const int lane = threadIdx.x & 63;
    if (tok >= NTOK) return;
    const float v0 = a1[(size_t)tok * 128 + lane];
    const float v1 = a1[(size_t)tok * 128 + 64 + lane];
    #pragma unroll
    for (int hp = 0; hp < 4; ++hp) {
        float s = v0 * cw2[lane * 4 + hp] + v1 * cw2[(64 + lane) * 4 + hp];
        #pragma unroll
        for (int o = 1; o < 64; o <<= 1) s += __shfl_xor(s, o);
        if (lane == 0) out[(size_t)tok * 4 + hp] = s + cb2[hp];
    }
}

__global__ void __launch_bounds__(512) softmaxT_kernel(const float* __restrict__ lgt,
        float* __restrict__ alpha, float* __restrict__ outAlpha)
{
    const int bh = blockIdx.x;           // b*4 + hop
    const int b = bh >> 2, hp = bh & 3;
    const int t = threadIdx.x;
    const float v = (t < 300) ? lgt[((size_t)(b * 300 + t)) * 4 + hp] : -1e30f;
    float m = v;
    #pragma unroll
    for (int o = 1; o < 64; o <<= 1) m = fmaxf(m, __shfl_xor(m, o));
    __shared__ float rm[8], rs[8];
    const int lane = t & 63, wid = t >> 6;
    if (lane == 0) rm[wid] = m;
    __syncthreads();
    m = rm[0];
    #pragma unroll
    for (int i = 1; i < 8; ++i) m = fmaxf(m, rm[i]);
    const float e = (t < 300) ? __expf(v - m) : 0.f;
    float s = e;
    #pragma unroll
    for (int o = 1; o < 64; o <<= 1) s += __shfl_xor(s, o);
    if (lane == 0) rs[wid] = s;
    __syncthreads();
    s = rs[0] + rs[1] + rs[2] + rs[3] + rs[4] + rs[5] + rs[6] + rs[7];
    if (t < 300) {
        const float a = e / s;
        alpha[(size_t)bh * 300 + t] = a;
        outAlpha[(size_t)bh * 300 + t] = a;
    }
}

__global__ void __launch_bounds__(256) pool_kernel(const float* __restrict__ alpha,
        const float* __restrict__ xln, float* __restrict__ wsp)
{
    const int bh = blockIdx.x, b = bh >> 2;
    const int d = blockIdx.y * 256 + threadIdx.x;
    const float* xp = xln + (size_t)b * 300 * 1024 + d;
    const float* al = alpha + (size_t)bh * 300;
    float acc = 0.f;
    for (int t = 0; t < 300; ++t) acc += al[t] * xp[(size_t)t * 1024];
    wsp[(size_t)bh * 1024 + d] = acc;
}

// =====================================================================
extern "C" void kernel_launch(void* const* d_in, const int* in_sizes, int n_in,
                              void* d_out, int out_size, void* d_ws, size_t ws_size,
                              hipStream_t stream)
{
    const float* rgb     = (const float*)d_in[0];
    const float* aud     = (const float*)d_in[1];
    const float* embed_W = (const float*)d_in[2];
    const float* embed_b = (const float*)d_in[3];
    const float* Wq      = (const float*)d_in[4];
    const float* bq      = (const float*)d_in[5];
    const float* Wk      = (const float*)d_in[6];
    const float* bk      = (const float*)d_in[7];
    const float* Wv      = (const float*)d_in[8];
    const float* bv      = (const float*)d_in[9];
    const float* Wo      = (const float*)d_in[10];
    const float* bo      = (const float*)d_in[11];
    const float* ln1_a   = (const float*)d_in[12];
    const float* ln1_b   = (const float*)d_in[13];
    const float* W1f     = (const float*)d_in[14];
    const float* b1f     = (const float*)d_in[15];
    const float* W2f     = (const float*)d_in[16];
    const float* b2f     = (const float*)d_in[17];
    const float* ln2_a   = (const float*)d_in[18];
    const float* ln2_b   = (const float*)d_in[19];
    const float* fn_a    = (const float*)d_in[20];
    const float* fn_b    = (const float*)d_in[21];
    const float* cw1     = (const float*)d_in[22];
    const float* cb1     = (const float*)d_in[23];
    const float* cw2     = (const float*)d_in[24];
    const float* cb2     = (const float*)d_in[25];
    const float* cw3     = (const float*)d_in[26];
    const float* cb3     = (const float*)d_in[27];
    const float* cw4     = (const float*)d_in[28];
    const float* cb4     = (const float*)d_in[29];

    char* base = (char*)d_ws;
    size_t off = 0;
    auto alloc = [&](size_t bytes) -> char* {
        char* p = base + off; off += (bytes + 255) & ~(size_t)255; return p; };

    float* x    = (float*)alloc((size_t)NTOK * DD * 4);        // 39.3 MB
    float* pe   = (float*)alloc((size_t)TT * DD * 4);          //  1.2 MB
    u16*  hbuf  = (u16*) alloc((size_t)NTOK * DD * 2);         // 19.7 MB (Ob aliases)
    u16*  Qb    = (u16*) alloc((size_t)NTOK * DD * 2);         // 19.7 MB  \ xln aliases Qb+Kb
    u16*  Kb    = (u16*) alloc((size_t)NTOK * DD * 2);         // 19.7 MB  /
    u16*  Vb    = (u16*) alloc((size_t)NTOK * DD * 2);         // 19.7 MB (xlnb aliases)
    u16*  pbuf  = (u16*) alloc((size_t)128 * 300 * TP * 2);    // 24.6 MB (attn chunk)
    u16*  midc  = (u16*) alloc((size_t)3200 * DFF * 2);        // 26.2 MB (featsb/a1 alias)
    float* lgts = (float*)alloc((size_t)NTOK * 4 * 4);
    float* alph = (float*)alloc((size_t)128 * 300 * 4);
    float* wsp  = (float*)alloc((size_t)32 * 4096 * 4);
    u16*  wsb   = (u16*) alloc((size_t)32 * 4096 * 2);
    u16*  t3b   = (u16*) alloc((size_t)32 * 4096 * 2);
    u16*  eWt   = (u16*) alloc((size_t)1024 * 1152 * 2);       //  2.4 MB
    u16*  WqT   = (u16*) alloc((size_t)1024 * 1024 * 2);       //  2.1 MB (one layer)
    u16*  WkT   = (u16*) alloc((size_t)1024 * 1024 * 2);
    u16*  WvT   = (u16*) alloc((size_t)1024 * 1024 * 2);
    u16*  WoT   = (u16*) alloc((size_t)1024 * 1024 * 2);
    u16*  W1T   = (u16*) alloc((size_t)4096 * 1024 * 2);       //  8.4 MB (one layer)
    u16*  W2T   = (u16*) alloc((size_t)1024 * 4096 * 2);       //  8.4 MB (one layer)
    u16*  c1T   = (u16*) alloc((size_t)128 * 1024 * 2);
    if (off > ws_size) return;   // ~199 MB total; loud failure if insufficient

    u16*  featsb = midc;          // 22.1 MB <= 26.2, dead after embed GEMM
    u16*  Ob     = hbuf;          // attention output (hbuf dead after QKV gemms)
    float* xln   = (float*)Qb;    // final-LN f32 output: spans Qb+Kb (both dead)
    u16*  xlnb   = Vb;            // final-LN bf16 output (Vb dead)
    float* a1    = (float*)midc;  // 4.9 MB, classifier phase (midc dead)
    float* outv     = (float*)d_out;
    float* outAlpha = outv + (size_t)32 * NCLS;

    const dim3 blk(256);

    pe_kernel<<<(TT * DD + 255) / 256, blk, 0, stream>>>(pe);
    feats_kernel<<<(int)(((size_t)NTOK * FIN + 255) / 256), blk, 0, stream>>>(rgb, aud, featsb);

    auto wconv = [&](const float* W, u16* Wt, int K, int N) {
        dim3 g((N + 31) / 32, (K + 31) / 32);
        wconv_kernel<<<g, dim3(32, 8), 0, stream>>>(W, Wt, K, N);
    };
    wconv(embed_W, eWt, FIN, DD);
    wconv(cw1, c1T, DD, DATT);

    // embed: x = (feats @ W + b)*sqrt(D) + PE
    gemm_k<EPI_EMBED><<<dim3(8, 75), blk, 0, stream>>>(featsb, eWt, embed_b, pe, x, nullptr, NTOK, DD, FIN);

    for (int i = 0; i < 4; ++i) {
        wconv(Wq  + (size_t)i * DD * DD,  WqT, DD, DD);
        wconv(Wk  + (size_t)i * DD * DD,  WkT, DD, DD);
        wconv(Wv  + (size_t)i * DD * DD,  WvT, DD, DD);
        wconv(Wo  + (size_t)i * DD * DD,  WoT, DD, DD);
        wconv(W1f + (size_t)i * DD * DFF, W1T, DD, DFF);
        wconv(W2f + (size_t)i * DFF * DD, W2T, DFF, DD);

        ln_kernel<0><<<NTOK, blk, 0, stream>>>(x, ln1_a + (size_t)i * DD, ln1_b + (size_t)i * DD, hbuf, nullptr);
        gemm_k<EPI_B_BF16><<<dim3(8, 75), blk, 0, stream>>>(hbuf, WqT, bq + (size_t)i * DD, nullptr, nullptr, Qb, NTOK, DD, DD);
        gemm_k<EPI_B_BF16><<<dim3(8, 75), blk, 0, stream>>>(hbuf, WkT, bk + (size_t)i * DD, nullptr, nullptr, Kb, NTOK, DD, DD);
        gemm_k<EPI_B_BF16><<<dim3(8, 75), blk, 0, stream>>>(hbuf, WvT, bv + (size_t)i * DD, nullptr, nullptr, Vb, NTOK, DD, DD);
        for (int c = 0; c < 2; ++c) {        // Ob = hbuf (dead now)
            attn_scores_kernel<<<128, blk, 0, stream>>>(Qb, Kb, pbuf, c * 128);
            attn_pv_kernel<<<128, blk, 0, stream>>>(pbuf, Vb, Ob, c * 128);
        }
        gemm_k<EPI_B_RES_F32><<<dim3(8, 75), blk, 0, stream>>>(Ob, WoT, bo + (size_t)i * DD, x, x, nullptr, NTOK, DD, DD);
        ln_kernel<0><<<NTOK, blk, 0, stream>>>(x, ln2_a + (size_t)i * DD, ln2_b + (size_t)i * DD, hbuf, nullptr);
        for (int c = 0; c < 3; ++c) {        // FFN in 3 chunks of 3200 tokens
            const size_t ro = (size_t)c * 3200;
            gemm_k<EPI_B_RELU_BF16><<<dim3(32, 25), blk, 0, stream>>>(hbuf + ro * DD, W1T, b1f + (size_t)i * DFF, nullptr, nullptr, midc, 3200, DFF, DD);
            gemm_k<EPI_B_RES_F32><<<dim3(8, 25), blk, 0, stream>>>(midc, W2T, b2f + (size_t)i * DD, x + ro * DD, x + ro * DD, nullptr, 3200, DD, DFF);
        }
    }

    ln_kernel<1><<<NTOK, blk, 0, stream>>>(x, fn_a, fn_b, xlnb, xln);
    gemm_k<EPI_B_TANH_F32><<<dim3(1, 75), blk, 0, stream>>>(xlnb, c1T, cb1, nullptr, a1, nullptr, NTOK, DATT, DD);
    logits_kernel<<<2400, blk, 0, stream>>>(a1, cw2, cb2, lgts);
    softmaxT_kernel<<<128, dim3(512), 0, stream>>>(lgts, alph, outAlpha);
    pool_kernel<<<dim3(128, 4), blk, 0, stream>>>(alph, xln, wsp);
    f2bf_kernel<<<(32 * 4096 + 255) / 256, blk, 0, stream>>>(wsp, wsb, 32 * 4096);
    gemm_nt<EPI_B_TANH_BF16><<<dim3(32, 1), blk, 0, stream>>>(wsb, cw3, cb3, nullptr, t3b, 32, 4096, 4096);
    gemm_nt<EPI_B_F32><<<dim3(31, 1), blk, 0, stream>>>(t3b, cw4, cb4, outv, nullptr, 32, NCLS, 4096);
}

// Round 3
// 3111.487 us; speedup vs baseline: 1.3984x; 1.3984x over previous
//
#include <hip/hip_runtime.h>
#include <stdint.h>

#define NTOK 9600
#define TT   300
#define DD   1024
#define HH   8
#define DFF  4096
#define FIN  1152
#define DATT 128
#define NCLS 3862
#define TP   320   // kv padded for PV k-steps
#define NQT  19    // ceil(304/16) tiles of 16

typedef unsigned short u16;
typedef __attribute__((ext_vector_type(8))) short short8;
typedef __attribute__((ext_vector_type(4))) float f32x4;

__device__ __forceinline__ int imin(int a, int b){ return a < b ? a : b; }

__device__ __forceinline__ u16 f2bf(float f){
    union { float f; uint32_t u; } v; v.f = f;
    uint32_t u = v.u;
    return (u16)((u + 0x7fffu + ((u >> 16) & 1u)) >> 16);
}

__device__ __forceinline__ f32x4 mfma16(short8 a, short8 b, f32x4 c){
    return __builtin_amdgcn_mfma_f32_16x16x32_bf16(a, b, c, 0, 0, 0);
}

// async global->LDS, 16B per lane. LDS dest must be wave-uniform base + lane*16 (linear).
__device__ __forceinline__ void gll16(const void* g, void* l){
    __builtin_amdgcn_global_load_lds((const __attribute__((address_space(1))) void*)g,
                                     (__attribute__((address_space(3))) void*)l, 16, 0, 0);
}

// ---------------- PE table ----------------
__global__ void __launch_bounds__(256) pe_kernel(float* __restrict__ pe)
{
    const int i = blockIdx.x * 256 + threadIdx.x;
    if (i >= TT * DD) return;
    const int t = i >> 10, d = i & 1023;
    const float fr = expf(-(float)(d & ~1) * (9.210340371976184f / 1024.0f));
    const float ang = (float)t * fr;
    pe[i] = (d & 1) ? cosf(ang) : sinf(ang);
}

// ---------------- feats concat + /255 -> bf16 ----------------
__global__ void __launch_bounds__(256) feats_kernel(const float* __restrict__ rgb,
        const float* __restrict__ aud, u16* __restrict__ out)
{
    const long i = (long)blockIdx.x * 256 + threadIdx.x;
    if (i >= (long)NTOK * FIN) return;
    const int row = (int)(i / FIN), c = (int)(i % FIN);
    const float v = (c < 1024) ? rgb[(size_t)row * 1024 + c] : aud[(size_t)row * 128 + (c - 1024)];
    out[i] = f2bf(v * (1.0f / 255.0f));
}

// ---------------- weight transpose + convert: W[K,N] f32 -> Wt[N,K] bf16 ----------------
__global__ void __launch_bounds__(256) wconv_kernel(const float* __restrict__ W,
        u16* __restrict__ Wt, int K, int N)
{
    __shared__ float tile[32][33];
    const int k0 = blockIdx.y * 32, n0 = blockIdx.x * 32;
    const int tx = threadIdx.x, ty = threadIdx.y;   // 32 x 8
    #pragma unroll
    for (int i = 0; i < 4; ++i) {
        const int k = k0 + ty + i * 8, n = n0 + tx;
        tile[ty + i * 8][tx] = (k < K && n < N) ? W[(size_t)k * N + n] : 0.f;
    }
    __syncthreads();
    #pragma unroll
    for (int i = 0; i < 4; ++i) {
        const int n = n0 + ty + i * 8, k = k0 + tx;
        if (n < N && k < K) Wt[(size_t)n * K + k] = f2bf(tile[tx][ty + i * 8]);
    }
}

// ---------------- f32 -> bf16 ----------------
__global__ void __launch_bounds__(256) f2bf_kernel(const float* __restrict__ in,
        u16* __restrict__ out, int n)
{
    const int i = blockIdx.x * 256 + threadIdx.x;
    if (i < n) out[i] = f2bf(in[i]);
}

// ---------------- LayerNorm (ddof=1, a*(x-m)/(std+eps)+b) ----------------
template<int WF>
__global__ void __launch_bounds__(256) ln_kernel(const float* __restrict__ xin,
        const float* __restrict__ ga, const float* __restrict__ gb,
        u16* __restrict__ ob, float* of)
{
    const int row = blockIdx.x, t = threadIdx.x;
    const float4 xv = *(const float4*)(xin + (size_t)row * 1024 + t * 4);
    float s1 = xv.x + xv.y + xv.z + xv.w;
    float s2 = xv.x * xv.x + xv.y * xv.y + xv.z * xv.z + xv.w * xv.w;
    #pragma unroll
    for (int o = 1; o < 64; o <<= 1) { s1 += __shfl_xor(s1, o); s2 += __shfl_xor(s2, o); }
    __shared__ float r1[4], r2[4];
    const int lane = t & 63, wid = t >> 6;
    if (lane == 0) { r1[wid] = s1; r2[wid] = s2; }
    __syncthreads();
    s1 = r1[0] + r1[1] + r1[2] + r1[3];
    s2 = r2[0] + r2[1] + r2[2] + r2[3];
    const float mean = s1 * (1.0f / 1024.0f);
    const float var  = (s2 - 1024.0f * mean * mean) * (1.0f / 1023.0f);
    const float inv  = 1.0f / (sqrtf(fmaxf(var, 0.f)) + 1e-6f);
    const float4 av  = *(const float4*)(ga + t * 4);
    const float4 bv  = *(const float4*)(gb + t * 4);
    const float y0 = av.x * (xv.x - mean) * inv + bv.x;
    const float y1 = av.y * (xv.y - mean) * inv + bv.y;
    const float y2 = av.z * (xv.z - mean) * inv + bv.z;
    const float y3 = av.w * (xv.w - mean) * inv + bv.w;
    ushort4 o4; o4.x = f2bf(y0); o4.y = f2bf(y1); o4.z = f2bf(y2); o4.w = f2bf(y3);
    *(ushort4*)(ob + (size_t)row * 1024 + t * 4) = o4;
    if (WF) {
        float4 yo; yo.x = y0; yo.y = y1; yo.z = y2; yo.w = y3;
        *(float4*)(of + (size_t)row * 1024 + t * 4) = yo;
    }
}

// ---------------- epilogue codes ----------------
#define EPI_EMBED        0
#define EPI_B_BF16       1
#define EPI_B_RELU_BF16  2
#define EPI_B_RES_F32    3
#define EPI_B_TANH_F32   4
#define EPI_ACC_F32      5   // outF = v + extra (no bias; FFN2 second half)
#define EPI_PART         6   // partials for split-K: outF[z*M*N + oi] = v

// ---- generic bf16 MFMA GEMM: C = A[M,K] * Bt[N,K]^T, global_load_lds staging (m97) ----
template<int EPI>
__global__ void __launch_bounds__(256) gemm_k(const u16* __restrict__ A, const u16* __restrict__ Bt,
        const float* __restrict__ bias, const float* extra,
        float* outF, u16* outB, int M, int N, int K,
        int lda, int ldb, int kchunk)
{
    __shared__ __align__(16) u16 As[4096];
    __shared__ __align__(16) u16 Bs[4096];
    const int tid = threadIdx.x;
    const int bm = blockIdx.y, bn = blockIdx.x;
    const int lane = tid & 63, wid = tid >> 6;
    const int lg = lane >> 4, lr = lane & 15;
    const int wr = wid >> 1, wc = wid & 1;

    int koff = 0, Keff = K;
    if (kchunk > 0) { koff = blockIdx.z * kchunk; Keff = kchunk; }

    const int srow = tid >> 2;
    const int skc  = (tid & 3) * 8;
    const u16* ap0 = A  + (size_t)imin(bm * 128 + srow,      M - 1) * lda + skc + koff;
    const u16* ap1 = A  + (size_t)imin(bm * 128 + srow + 64, M - 1) * lda + skc + koff;
    const u16* bp0 = Bt + (size_t)imin(bn * 128 + srow,      N - 1) * ldb + skc + koff;
    const u16* bp1 = Bt + (size_t)imin(bn * 128 + srow + 64, N - 1) * ldb + skc + koff;

    f32x4 acc[4][4] = {};

    for (int k0 = 0; k0 < Keff; k0 += 32) {
        __syncthreads();                      // LDS free to overwrite
        gll16(ap0 + k0, As + tid * 8);
        gll16(ap1 + k0, As + 2048 + tid * 8);
        gll16(bp0 + k0, Bs + tid * 8);
        gll16(bp1 + k0, Bs + 2048 + tid * 8);
        __syncthreads();                      // vmcnt(0) drained before barrier -> data ready
        short8 af[4], bf[4];
        #pragma unroll
        for (int m = 0; m < 4; ++m)
            af[m] = *(const short8*)(As + (wr * 64 + m * 16 + lr) * 32 + lg * 8);
        #pragma unroll
        for (int n = 0; n < 4; ++n)
            bf[n] = *(const short8*)(Bs + (wc * 64 + n * 16 + lr) * 32 + lg * 8);
        #pragma unroll
        for (int m = 0; m < 4; ++m)
            #pragma unroll
            for (int n = 0; n < 4; ++n)
                acc[m][n] = mfma16(af[m], bf[n], acc[m][n]);
    }

    #pragma unroll
    for (int m = 0; m < 4; ++m) {
        const int rb = bm * 128 + wr * 64 + m * 16 + lg * 4;
        #pragma unroll
        for (int n = 0; n < 4; ++n) {
            const int col = bn * 128 + wc * 64 + n * 16 + lr;
            if (col >= N) continue;
            const float bvl = (EPI == EPI_PART || EPI == EPI_ACC_F32) ? 0.f : bias[col];
            #pragma unroll
            for (int j = 0; j < 4; ++j) {
                const int r = rb + j;
                if (r >= M) continue;
                const float v = acc[m][n][j];
                const size_t oi = (size_t)r * N + col;
                if      (EPI == EPI_EMBED)       outF[oi] = (v + bvl) * 32.0f + extra[(size_t)(r % 300) * 1024 + col];
                else if (EPI == EPI_B_BF16)      outB[oi] = f2bf(v + bvl);
                else if (EPI == EPI_B_RELU_BF16) outB[oi] = f2bf(fmaxf(v + bvl, 0.f));
                else if (EPI == EPI_B_RES_F32)   outF[oi] = v + bvl + extra[oi];
                else if (EPI == EPI_B_TANH_F32)  outF[oi] = tanhf(v + bvl);
                else if (EPI == EPI_ACC_F32)     outF[oi] = v + extra[oi];
                else if (EPI == EPI_PART)        outF[(size_t)blockIdx.z * M * N + oi] = v;
            }
        }
    }
}

// ---------------- split-K reduce + bias (+tanh) ----------------
template<int TANH>
__global__ void __launch_bounds__(256) redk_kernel(const float* __restrict__ part,
        const float* __restrict__ bias, float* outF, u16* outB, int M, int N, int Z)
{
    const int i = blockIdx.x * 256 + threadIdx.x;
    if (i >= M * N) return;
    const int col = i % N;
    float s = 0.f;
    for (int z = 0; z < Z; ++z) s += part[(size_t)z * M * N + i];
    s += bias[col];
    if (TANH) outB[i] = f2bf(tanhf(s));
    else      outF[i] = s;
}

// ---------------- attention: scores + softmax -> P bf16 (chunk of bh) ----------------
__global__ void __launch_bounds__(256) attn_scores_kernel(const u16* __restrict__ Qb,
        const u16* __restrict__ Kb, u16* __restrict__ P, int bh0)
{
    __shared__ __align__(16) u16 Ks[304 * 128];   // 77824 B, XOR-swizzled rows
    const int bh = bh0 + blockIdx.x, b = bh >> 3, h = bh & 7;
    const int tid = threadIdx.x, lane = tid & 63, wid = tid >> 6;
    const int lg = lane >> 4, lr = lane & 15;

    for (int c = tid; c < 304 * 16; c += 256) {
        const int kv = c >> 4, part = c & 15;
        const int tok = b * 300 + imin(kv, 299);
        const short8 v = *(const short8*)(Kb + (size_t)tok * 1024 + h * 128 + part * 8);
        int byte_ = kv * 256 + part * 16;
        byte_ ^= (kv & 7) << 4;
        *(short8*)((char*)Ks + byte_) = v;
    }
    __syncthreads();

    const float scale = 0.08838834764831845f;   // 1/sqrt(128)
    for (int qt = wid; qt < NQT; qt += 4) {
        f32x4 acc[NQT] = {};
        const int qtok = b * 300 + imin(qt * 16 + lr, 299);
        const u16* qrow = Qb + (size_t)qtok * 1024 + h * 128;
        #pragma unroll
        for (int kk = 0; kk < 4; ++kk) {
            const short8 aq = *(const short8*)(qrow + kk * 32 + lg * 8);
            #pragma unroll
            for (int nt = 0; nt < NQT; ++nt) {
                const int kvrow = nt * 16 + lr;
                int byte_ = kvrow * 256 + kk * 64 + lg * 16;
                byte_ ^= (kvrow & 7) << 4;
                const short8 bk = *(const short8*)((char*)Ks + byte_);
                acc[nt] = mfma16(aq, bk, acc[nt]);
            }
        }
        #pragma unroll
        for (int j = 0; j < 4; ++j) {
            float vals[NQT];
            float m = -1e30f;
            #pragma unroll
            for (int nt = 0; nt < NQT; ++nt) {
                float s = acc[nt][j] * scale;
                if (nt * 16 + lr >= 300) s = -1e30f;
                vals[nt] = s;
                m = fmaxf(m, s);
            }
            #pragma unroll
            for (int o = 1; o < 16; o <<= 1) m = fmaxf(m, __shfl_xor(m, o));
            float sum = 0.f;
            #pragma unroll
            for (int nt = 0; nt < NQT; ++nt) { const float e = __expf(vals[nt] - m); vals[nt] = e; sum += e; }
            #pragma unroll
            for (int o = 1; o < 16; o <<= 1) sum += __shfl_xor(sum, o);
            const float inv = 1.0f / sum;
            const int q = qt * 16 + lg * 4 + j;
            if (q < 300) {
                u16* prow = P + ((size_t)blockIdx.x * 300 + q) * TP;
                #pragma unroll
                for (int nt = 0; nt < NQT; ++nt) prow[nt * 16 + lr] = f2bf(vals[nt] * inv);
                prow[304 + lr] = 0;   // zero kv pad 304..319
            }
        }
    }
}

// ---------------- attention: O = P @ V (chunk of bh) ----------------
__global__ void __launch_bounds__(256) attn_pv_kernel(const u16* __restrict__ P,
        const u16* __restrict__ Vb, u16* __restrict__ O, int bh0)
{
    __shared__ __align__(16) u16 Vs[128 * TP];   // V^T, 81920 B, XOR-swizzled rows
    const int bh = bh0 + blockIdx.x, b = bh >> 3, h = bh & 7;
    const int tid = threadIdx.x, lane = tid & 63, wid = tid >> 6;
    const int lg = lane >> 4, lr = lane & 15;

    for (int c = tid; c < 304 * 16; c += 256) {
        const int kv = c >> 4, dp = c & 15;
        const int tok = b * 300 + imin(kv, 299);
        const short8 v = *(const short8*)(Vb + (size_t)tok * 1024 + h * 128 + dp * 8);
        #pragma unroll
        for (int jj = 0; jj < 8; ++jj) {
            const int d = dp * 8 + jj;
            int byte_ = d * (TP * 2) + kv * 2;
            byte_ ^= (d & 7) << 4;
            *(u16*)((char*)Vs + byte_) = (u16)v[jj];
        }
    }
    for (int c = tid; c < 128 * 16; c += 256) {     // zero kv pad 304..319
        const int d = c >> 4, kv = 304 + (c & 15);
        int byte_ = d * (TP * 2) + kv * 2;
        byte_ ^= (d & 7) << 4;
        *(u16*)((char*)Vs + byte_) = 0;
    }
    __syncthreads();

    for (int qt = wid; qt < NQT; qt += 4) {
        f32x4 acc[8] = {};
        const int q = imin(qt * 16 + lr, 299);
        const u16* prow = P + ((size_t)blockIdx.x * 300 + q) * TP;
        #pragma unroll
        for (int kk = 0; kk < 10; ++kk) {
            const short8 ap = *(const short8*)(prow + kk * 32 + lg * 8);
            #pragma unroll
            for (int nt = 0; nt < 8; ++nt) {
                const int d = nt * 16 + lr;
                int byte_ = d * (TP * 2) + kk * 64 + lg * 16;
                byte_ ^= (d & 7) << 4;
                const short8 bv8 = *(const short8*)((char*)Vs + byte_);
                acc[nt] = mfma16(ap, bv8, acc[nt]);
            }
        }
        #pragma unroll
        for (int nt = 0; nt < 8; ++nt) {
            #pragma unroll
            for (int j = 0; j < 4; ++j) {
                const int qq = qt * 16 + lg * 4 + j;
                if (qq < 300)
                    O[((size_t)(b * 300 + qq)) * 1024 + h * 128 + nt * 16 + lr] = f2bf(acc[nt][j]);
            }
        }
    }
}

// ---------------- classifier tail ----------------
__global__ void __launch_bounds__(256) logits_kernel(const float* __restrict__ a1,
        const float* __restrict__ cw2, const float* __restrict__ cb2, float* __restrict__ out)
{
    const int tok = blockIdx.x * 4 + (threadIdx.x >> 6);
    const int lane = threadIdx.x & 63;
    if (tok >= NTOK) return;
    const float v0 = a1[(size_t)tok * 128 + lane];
    const float v1 = a1[(size_t)tok * 128 + 64 + lane];
    #pragma unroll
    for (int hp = 0; hp < 4; ++hp) {
        float s = v0 * cw2[lane * 4 + hp] + v1 * cw2[(64 + lane) * 4 + hp];
        #pragma unroll
        for (int o = 1; o < 64; o <<= 1) s += __shfl_xor(s, o);
        if (lane == 0) out[(size_t)tok * 4 + hp] = s + cb2[hp];
    }
}

__global__ void __launch_bounds__(512) softmaxT_kernel(const float* __restrict__ lgt,
        float* __restrict__ alpha, float* __restrict__ outAlpha)
{
    const int bh = blockIdx.x;           // b*4 + hop
    const int b = bh >> 2, hp = bh & 3;
    const int t = threadIdx.x;
    const float v = (t < 300) ? lgt[((size_t)(b * 300 + t)) * 4 + hp] : -1e30f;
    float m = v;
    #pragma unroll
    for (int o = 1; o < 64; o <<= 1) m = fmaxf(m, __shfl_xor(m, o));
    __shared__ float rm[8], rs[8];
    const int lane = t & 63, wid = t >> 6;
    if (lane == 0) rm[wid] = m;
    __syncthreads();
    m = rm[0];
    #pragma unroll
    for (int i = 1; i < 8; ++i) m = fmaxf(m, rm[i]);
    const float e = (t < 300) ? __expf(v - m) : 0.f;
    float s = e;
    #pragma unroll
    for (int o = 1; o < 64; o <<= 1) s += __shfl_xor(s, o);
    if (lane == 0) rs[wid] = s;
    __syncthreads();
    s = rs[0] + rs[1] + rs[2] + rs[3] + rs[4] + rs[5] + rs[6] + rs[7];
    if (t < 300) {
        const float a = e / s;
        alpha[(size_t)bh * 300 + t] = a;
        outAlpha[(size_t)bh * 300 + t] = a;
    }
}

__global__ void __launch_bounds__(256) pool_kernel(const float* __restrict__ alpha,
        const float* __restrict__ xln, float* __restrict__ wsp)
{
    const int bh = blockIdx.x, b = bh >> 2;
    const int d = blockIdx.y * 256 + threadIdx.x;
    const float* xp = xln + (size_t)b * 300 * 1024 + d;
    const float* al = alpha + (size_t)bh * 300;
    float acc = 0.f;
    for (int t = 0; t < 300; ++t) acc += al[t] * xp[(size_t)t * 1024];
    wsp[(size_t)bh * 1024 + d] = acc;
}

// =====================================================================
extern "C" void kernel_launch(void* const* d_in, const int* in_sizes, int n_in,
                              void* d_out, int out_size, void* d_ws, size_t ws_size,
                              hipStream_t stream)
{
    const float* rgb     = (const float*)d_in[0];
    const float* aud     = (const float*)d_in[1];
    const float* embed_W = (const float*)d_in[2];
    const float* embed_b = (const float*)d_in[3];
    const float* Wq      = (const float*)d_in[4];
    const float* bq      = (const float*)d_in[5];
    const float* Wk      = (const float*)d_in[6];
    const float* bk      = (const float*)d_in[7];
    const float* Wv      = (const float*)d_in[8];
    const float* bv      = (const float*)d_in[9];
    const float* Wo      = (const float*)d_in[10];
    const float* bo      = (const float*)d_in[11];
    const float* ln1_a   = (const float*)d_in[12];
    const float* ln1_b   = (const float*)d_in[13];
    const float* W1f     = (const float*)d_in[14];
    const float* b1f     = (const float*)d_in[15];
    const float* W2f     = (const float*)d_in[16];
    const float* b2f     = (const float*)d_in[17];
    const float* ln2_a   = (const float*)d_in[18];
    const float* ln2_b   = (const float*)d_in[19];
    const float* fn_a    = (const float*)d_in[20];
    const float* fn_b    = (const float*)d_in[21];
    const float* cw1     = (const float*)d_in[22];
    const float* cb1     = (const float*)d_in[23];
    const float* cw2     = (const float*)d_in[24];
    const float* cb2     = (const float*)d_in[25];
    const float* cw3     = (const float*)d_in[26];
    const float* cb3     = (const float*)d_in[27];
    const float* cw4     = (const float*)d_in[28];
    const float* cb4     = (const float*)d_in[29];

    char* base = (char*)d_ws;
    size_t off = 0;
    auto alloc = [&](size_t bytes) -> char* {
        char* p = base + off; off += (bytes + 255) & ~(size_t)255; return p; };

    float* x    = (float*)alloc((size_t)NTOK * DD * 4);        // 39.3 MB (c3T aliases after final LN)
    float* pe   = (float*)alloc((size_t)TT * DD * 4);          //  1.2 MB
    u16*  hbuf  = (u16*) alloc((size_t)NTOK * DD * 2);         // 19.7 MB (Ob, splitK partials alias)
    u16*  Qb    = (u16*) alloc((size_t)NTOK * DD * 2);         // 19.7 MB  \ xln aliases Qb+Kb
    u16*  Kb    = (u16*) alloc((size_t)NTOK * DD * 2);         // 19.7 MB  /
    u16*  Vb    = (u16*) alloc((size_t)NTOK * DD * 2);         // 19.7 MB (xlnb aliases)
    u16*  S     = (u16*) alloc((size_t)NTOK * (DFF/2) * 2);    // 39.3 MB shared: feats/pbuf/midc/a1/c4T
    float* lgts = (float*)alloc((size_t)NTOK * 4 * 4);
    float* alph = (float*)alloc((size_t)128 * 300 * 4);
    float* wsp  = (float*)alloc((size_t)32 * 4096 * 4);
    u16*  wsb   = (u16*) alloc((size_t)32 * 4096 * 2);
    u16*  t3b   = (u16*) alloc((size_t)32 * 4096 * 2);
    u16*  eWt   = (u16*) alloc((size_t)1024 * 1152 * 2);       //  2.4 MB
    u16*  WqT   = (u16*) alloc((size_t)1024 * 1024 * 2);       //  2.1 MB (per-layer reuse)
    u16*  WkT   = (u16*) alloc((size_t)1024 * 1024 * 2);
    u16*  WvT   = (u16*) alloc((size_t)1024 * 1024 * 2);
    u16*  WoT   = (u16*) alloc((size_t)1024 * 1024 * 2);
    u16*  W1T   = (u16*) alloc((size_t)DFF * DD * 2);          //  8.4 MB [DFF rows, DD]
    u16*  W2T   = (u16*) alloc((size_t)DD * DFF * 2);          //  8.4 MB [DD rows, DFF]
    u16*  c1T   = (u16*) alloc((size_t)128 * 1024 * 2);
    if (off > ws_size) return;   // ~188 MB total; loud failure if insufficient

    u16*  featsb = S;             // 22.1 MB, dead after embed GEMM
    u16*  pbuf   = S;             // 24.6 MB, attn P (dead outside attn)
    u16*  midc   = S;             // 39.3 MB, FFN half-activation
    u16*  Ob     = hbuf;          // attention output (hbuf dead after QKV gemms)
    float* xln   = (float*)Qb;    // final-LN f32 output: spans Qb+Kb (both dead)
    u16*  xlnb   = Vb;            // final-LN bf16 output (Vb dead)
    float* a1    = (float*)S;     // 4.9 MB, classifier phase
    u16*  c3T    = (u16*)x;       // 32.0 MB  <= 39.3 (x dead after final LN)
    u16*  c4T    = S;             // 30.2 MB  <= 39.3 (written after logits; a1 dead)
    float* part  = (float*)hbuf;  // split-K partials, <=4.1 MB (hbuf dead in classifier)
    float* outv     = (float*)d_out;
    float* outAlpha = outv + (size_t)32 * NCLS;

    const dim3 blk(256);

    pe_kernel<<<(TT * DD + 255) / 256, blk, 0, stream>>>(pe);
    feats_kernel<<<(int)(((size_t)NTOK * FIN + 255) / 256), blk, 0, stream>>>(rgb, aud, featsb);

    auto wconv = [&](const float* W, u16* Wt, int K, int N) {
        dim3 g((N + 31) / 32, (K + 31) / 32);
        wconv_kernel<<<g, dim3(32, 8), 0, stream>>>(W, Wt, K, N);
    };
    wconv(embed_W, eWt, FIN, DD);
    wconv(cw1, c1T, DD, DATT);

    // embed: x = (feats @ W + b)*sqrt(D) + PE
    gemm_k<EPI_EMBED><<<dim3(8, 75), blk, 0, stream>>>(featsb, eWt, embed_b, pe, x, nullptr,
                                                       NTOK, DD, FIN, FIN, FIN, 0);

    for (int i = 0; i < 4; ++i) {
        wconv(Wq  + (size_t)i * DD * DD,  WqT, DD, DD);
        wconv(Wk  + (size_t)i * DD * DD,  WkT, DD, DD);
        wconv(Wv  + (size_t)i * DD * DD,  WvT, DD, DD);
        wconv(Wo  + (size_t)i * DD * DD,  WoT, DD, DD);
        wconv(W1f + (size_t)i * DD * DFF, W1T, DD, DFF);
        wconv(W2f + (size_t)i * DFF * DD, W2T, DFF, DD);

        ln_kernel<0><<<NTOK, blk, 0, stream>>>(x, ln1_a + (size_t)i * DD, ln1_b + (size_t)i * DD, hbuf, nullptr);
        gemm_k<EPI_B_BF16><<<dim3(8, 75), blk, 0, stream>>>(hbuf, WqT, bq + (size_t)i * DD, nullptr, nullptr, Qb,
                                                            NTOK, DD, DD, DD, DD, 0);
        gemm_k<EPI_B_BF16><<<dim3(8, 75), blk, 0, stream>>>(hbuf, WkT, bk + (size_t)i * DD, nullptr, nullptr, Kb,
                                                            NTOK, DD, DD, DD, DD, 0);
        gemm_k<EPI_B_BF16><<<dim3(8, 75), blk, 0, stream>>>(hbuf, WvT, bv + (size_t)i * DD, nullptr, nullptr, Vb,
                                                            NTOK, DD, DD, DD, DD, 0);
        for (int c = 0; c < 2; ++c) {        // Ob = hbuf (dead now)
            attn_scores_kernel<<<128, blk, 0, stream>>>(Qb, Kb, pbuf, c * 128);
            attn_pv_kernel<<<128, blk, 0, stream>>>(pbuf, Vb, Ob, c * 128);
        }
        gemm_k<EPI_B_RES_F32><<<dim3(8, 75), blk, 0, stream>>>(Ob, WoT, bo + (size_t)i * DD, x, x, nullptr,
                                                               NTOK, DD, DD, DD, DD, 0);
        ln_kernel<0><<<NTOK, blk, 0, stream>>>(x, ln2_a + (size_t)i * DD, ln2_b + (size_t)i * DD, hbuf, nullptr);
        // FFN split over DFF halves: midc holds [9600, 2048]
        for (int h = 0; h < 2; ++h) {
            gemm_k<EPI_B_RELU_BF16><<<dim3(16, 75), blk, 0, stream>>>(hbuf, W1T + (size_t)h * 2048 * DD,
                    b1f + (size_t)i * DFF + h * 2048, nullptr, nullptr, midc,
                    NTOK, 2048, DD, DD, DD, 0);
            if (h == 0)
                gemm_k<EPI_B_RES_F32><<<dim3(8, 75), blk, 0, stream>>>(midc, W2T + (size_t)h * 2048,
                        b2f + (size_t)i * DD, x, x, nullptr, NTOK, DD, 2048, 2048, DFF, 0);
            else
                gemm_k<EPI_ACC_F32><<<dim3(8, 75), blk, 0, stream>>>(midc, W2T + (size_t)h * 2048,
                        b2f + (size_t)i * DD, x, x, nullptr, NTOK, DD, 2048, 2048, DFF, 0);
        }
    }

    ln_kernel<1><<<NTOK, blk, 0, stream>>>(x, fn_a, fn_b, xlnb, xln);
    wconv(cw3, c3T, 4096, DFF);                               // x dead -> c3T
    gemm_k<EPI_B_TANH_F32><<<dim3(1, 75), blk, 0, stream>>>(xlnb, c1T, cb1, nullptr, a1, nullptr,
                                                            NTOK, DATT, DD, DD, DD, 0);
    logits_kernel<<<2400, blk, 0, stream>>>(a1, cw2, cb2, lgts);
    wconv(cw4, c4T, DFF, NCLS);                               // a1 dead -> c4T
    softmaxT_kernel<<<128, dim3(512), 0, stream>>>(lgts, alph, outAlpha);
    pool_kernel<<<dim3(128, 4), blk, 0, stream>>>(alph, xln, wsp);
    f2bf_kernel<<<(32 * 4096 + 255) / 256, blk, 0, stream>>>(wsp, wsb, 32 * 4096);

    // classifier GEMMs: split-K (Z=8, Kc=512), deterministic reduce
    gemm_k<EPI_PART><<<dim3(32, 1, 8), blk, 0, stream>>>(wsb, c3T, nullptr, nullptr, part, nullptr,
                                                         32, 4096, 4096, 4096, 4096, 512);
    redk_kernel<1><<<(32 * 4096 + 255) / 256, blk, 0, stream>>>(part, cb3, nullptr, t3b, 32, 4096, 8);
    gemm_k<EPI_PART><<<dim3(31, 1, 8), blk, 0, stream>>>(t3b, c4T, nullptr, nullptr, part, nullptr,
                                                         32, NCLS, 4096, 4096, 4096, 512);
    redk_kernel<0><<<(32 * NCLS + 255) / 256, blk, 0, stream>>>(part, cb4, outv, nullptr, 32, NCLS, 8);
}

// Round 4
// 2707.388 us; speedup vs baseline: 1.6072x; 1.1493x over previous
//
#include <hip/hip_runtime.h>
#include <stdint.h>

#define NTOK 9600
#define TT   300
#define DD   1024
#define HH   8
#define DFF  4096
#define FIN  1152
#define DATT 128
#define NCLS 3862
#define TP   320   // kv padded for PV k-steps
#define NQT  19    // ceil(304/16) tiles of 16

typedef unsigned short u16;
typedef __attribute__((ext_vector_type(8))) short short8;
typedef __attribute__((ext_vector_type(4))) float f32x4;

__device__ __forceinline__ int imin(int a, int b){ return a < b ? a : b; }

__device__ __forceinline__ u16 f2bf(float f){
    union { float f; uint32_t u; } v; v.f = f;
    uint32_t u = v.u;
    return (u16)((u + 0x7fffu + ((u >> 16) & 1u)) >> 16);
}

__device__ __forceinline__ f32x4 mfma16(short8 a, short8 b, f32x4 c){
    return __builtin_amdgcn_mfma_f32_16x16x32_bf16(a, b, c, 0, 0, 0);
}

// async global->LDS, 16B per lane. LDS dest must be wave-uniform base + lane*16 (linear).
__device__ __forceinline__ void gll16(const void* g, void* l){
    __builtin_amdgcn_global_load_lds((const __attribute__((address_space(1))) void*)g,
                                     (__attribute__((address_space(3))) void*)l, 16, 0, 0);
}

// ---------------- PE table ----------------
__global__ void __launch_bounds__(256) pe_kernel(float* __restrict__ pe)
{
    const int i = blockIdx.x * 256 + threadIdx.x;
    if (i >= TT * DD) return;
    const int t = i >> 10, d = i & 1023;
    const float fr = expf(-(float)(d & ~1) * (9.210340371976184f / 1024.0f));
    const float ang = (float)t * fr;
    pe[i] = (d & 1) ? cosf(ang) : sinf(ang);
}

// ---------------- feats concat + /255 -> bf16 ----------------
__global__ void __launch_bounds__(256) feats_kernel(const float* __restrict__ rgb,
        const float* __restrict__ aud, u16* __restrict__ out)
{
    const long i = (long)blockIdx.x * 256 + threadIdx.x;
    if (i >= (long)NTOK * FIN) return;
    const int row = (int)(i / FIN), c = (int)(i % FIN);
    const float v = (c < 1024) ? rgb[(size_t)row * 1024 + c] : aud[(size_t)row * 128 + (c - 1024)];
    out[i] = f2bf(v * (1.0f / 255.0f));
}

// ---------------- weight transpose + convert: W[K,N] f32 -> Wt[N,K] bf16 ----------------
__global__ void __launch_bounds__(256) wconv_kernel(const float* __restrict__ W,
        u16* __restrict__ Wt, int K, int N)
{
    __shared__ float tile[32][33];
    const int k0 = blockIdx.y * 32, n0 = blockIdx.x * 32;
    const int tx = threadIdx.x, ty = threadIdx.y;   // 32 x 8
    #pragma unroll
    for (int i = 0; i < 4; ++i) {
        const int k = k0 + ty + i * 8, n = n0 + tx;
        tile[ty + i * 8][tx] = (k < K && n < N) ? W[(size_t)k * N + n] : 0.f;
    }
    __syncthreads();
    #pragma unroll
    for (int i = 0; i < 4; ++i) {
        const int n = n0 + ty + i * 8, k = k0 + tx;
        if (n < N && k < K) Wt[(size_t)n * K + k] = f2bf(tile[tx][ty + i * 8]);
    }
}

// ---------------- f32 -> bf16 ----------------
__global__ void __launch_bounds__(256) f2bf_kernel(const float* __restrict__ in,
        u16* __restrict__ out, int n)
{
    const int i = blockIdx.x * 256 + threadIdx.x;
    if (i < n) out[i] = f2bf(in[i]);
}

// ---------------- LayerNorm (ddof=1, a*(x-m)/(std+eps)+b) ----------------
template<int WF>
__global__ void __launch_bounds__(256) ln_kernel(const float* __restrict__ xin,
        const float* __restrict__ ga, const float* __restrict__ gb,
        u16* __restrict__ ob, float* of)
{
    const int row = blockIdx.x, t = threadIdx.x;
    const float4 xv = *(const float4*)(xin + (size_t)row * 1024 + t * 4);
    float s1 = xv.x + xv.y + xv.z + xv.w;
    float s2 = xv.x * xv.x + xv.y * xv.y + xv.z * xv.z + xv.w * xv.w;
    #pragma unroll
    for (int o = 1; o < 64; o <<= 1) { s1 += __shfl_xor(s1, o); s2 += __shfl_xor(s2, o); }
    __shared__ float r1[4], r2[4];
    const int lane = t & 63, wid = t >> 6;
    if (lane == 0) { r1[wid] = s1; r2[wid] = s2; }
    __syncthreads();
    s1 = r1[0] + r1[1] + r1[2] + r1[3];
    s2 = r2[0] + r2[1] + r2[2] + r2[3];
    const float mean = s1 * (1.0f / 1024.0f);
    const float var  = (s2 - 1024.0f * mean * mean) * (1.0f / 1023.0f);
    const float inv  = 1.0f / (sqrtf(fmaxf(var, 0.f)) + 1e-6f);
    const float4 av  = *(const float4*)(ga + t * 4);
    const float4 bv  = *(const float4*)(gb + t * 4);
    const float y0 = av.x * (xv.x - mean) * inv + bv.x;
    const float y1 = av.y * (xv.y - mean) * inv + bv.y;
    const float y2 = av.z * (xv.z - mean) * inv + bv.z;
    const float y3 = av.w * (xv.w - mean) * inv + bv.w;
    ushort4 o4; o4.x = f2bf(y0); o4.y = f2bf(y1); o4.z = f2bf(y2); o4.w = f2bf(y3);
    *(ushort4*)(ob + (size_t)row * 1024 + t * 4) = o4;
    if (WF) {
        float4 yo; yo.x = y0; yo.y = y1; yo.z = y2; yo.w = y3;
        *(float4*)(of + (size_t)row * 1024 + t * 4) = yo;
    }
}

// ---------------- epilogue codes ----------------
#define EPI_EMBED        0
#define EPI_B_BF16       1
#define EPI_B_RELU_BF16  2
#define EPI_B_RES_F32    3
#define EPI_B_TANH_F32   4
#define EPI_ACC_F32      5   // outF = v + extra (no bias; FFN2 second half)
#define EPI_PART         6   // partials for split-K: outF[z*M*N + oi] = v

// ---- generic bf16 MFMA GEMM: C = A[M,K] * Bt[N,K]^T, global_load_lds staging (m97) ----
// SWZ=1: XCD-aware block remap (T1) — row-panel-major chunks per XCD; grid.x*grid.y % 8 == 0.
template<int EPI, int SWZ>
__global__ void __launch_bounds__(256) gemm_k(const u16* __restrict__ A, const u16* __restrict__ Bt,
        const float* __restrict__ bias, const float* extra,
        float* outF, u16* outB, int M, int N, int K,
        int lda, int ldb, int kchunk)
{
    __shared__ __align__(16) u16 As[4096];
    __shared__ __align__(16) u16 Bs[4096];
    const int tid = threadIdx.x;
    int bm, bn;
    if (SWZ) {
        int lin = blockIdx.y * gridDim.x + blockIdx.x;
        const int nwg = gridDim.x * gridDim.y;
        const int cpx = nwg >> 3;
        lin = (lin & 7) * cpx + (lin >> 3);
        bm = lin / gridDim.x;
        bn = lin - bm * gridDim.x;
    } else {
        bm = blockIdx.y; bn = blockIdx.x;
    }
    const int lane = tid & 63, wid = tid >> 6;
    const int lg = lane >> 4, lr = lane & 15;
    const int wr = wid >> 1, wc = wid & 1;

    int koff = 0, Keff = K;
    if (kchunk > 0) { koff = blockIdx.z * kchunk; Keff = kchunk; }

    const int srow = tid >> 2;
    const int skc  = (tid & 3) * 8;
    const u16* ap0 = A  + (size_t)imin(bm * 128 + srow,      M - 1) * lda + skc + koff;
    const u16* ap1 = A  + (size_t)imin(bm * 128 + srow + 64, M - 1) * lda + skc + koff;
    const u16* bp0 = Bt + (size_t)imin(bn * 128 + srow,      N - 1) * ldb + skc + koff;
    const u16* bp1 = Bt + (size_t)imin(bn * 128 + srow + 64, N - 1) * ldb + skc + koff;

    f32x4 acc[4][4] = {};

    for (int k0 = 0; k0 < Keff; k0 += 32) {
        __syncthreads();                      // LDS free to overwrite
        gll16(ap0 + k0, As + tid * 8);
        gll16(ap1 + k0, As + 2048 + tid * 8);
        gll16(bp0 + k0, Bs + tid * 8);
        gll16(bp1 + k0, Bs + 2048 + tid * 8);
        __syncthreads();                      // vmcnt(0) drained before barrier -> data ready
        short8 af[4], bf[4];
        #pragma unroll
        for (int m = 0; m < 4; ++m)
            af[m] = *(const short8*)(As + (wr * 64 + m * 16 + lr) * 32 + lg * 8);
        #pragma unroll
        for (int n = 0; n < 4; ++n)
            bf[n] = *(const short8*)(Bs + (wc * 64 + n * 16 + lr) * 32 + lg * 8);
        #pragma unroll
        for (int m = 0; m < 4; ++m)
            #pragma unroll
            for (int n = 0; n < 4; ++n)
                acc[m][n] = mfma16(af[m], bf[n], acc[m][n]);
    }

    #pragma unroll
    for (int m = 0; m < 4; ++m) {
        const int rb = bm * 128 + wr * 64 + m * 16 + lg * 4;
        #pragma unroll
        for (int n = 0; n < 4; ++n) {
            const int col = bn * 128 + wc * 64 + n * 16 + lr;
            if (col >= N) continue;
            const float bvl = (EPI == EPI_PART || EPI == EPI_ACC_F32) ? 0.f : bias[col];
            #pragma unroll
            for (int j = 0; j < 4; ++j) {
                const int r = rb + j;
                if (r >= M) continue;
                const float v = acc[m][n][j];
                const size_t oi = (size_t)r * N + col;
                if      (EPI == EPI_EMBED)       outF[oi] = (v + bvl) * 32.0f + extra[(size_t)(r % 300) * 1024 + col];
                else if (EPI == EPI_B_BF16)      outB[oi] = f2bf(v + bvl);
                else if (EPI == EPI_B_RELU_BF16) outB[oi] = f2bf(fmaxf(v + bvl, 0.f));
                else if (EPI == EPI_B_RES_F32)   outF[oi] = v + bvl + extra[oi];
                else if (EPI == EPI_B_TANH_F32)  outF[oi] = tanhf(v + bvl);
                else if (EPI == EPI_ACC_F32)     outF[oi] = v + extra[oi];
                else if (EPI == EPI_PART)        outF[(size_t)blockIdx.z * M * N + oi] = v;
            }
        }
    }
}

// ---------------- split-K reduce + bias (+tanh) ----------------
template<int TANH>
__global__ void __launch_bounds__(256) redk_kernel(const float* __restrict__ part,
        const float* __restrict__ bias, float* outF, u16* outB, int M, int N, int Z)
{
    const int i = blockIdx.x * 256 + threadIdx.x;
    if (i >= M * N) return;
    const int col = i % N;
    float s = 0.f;
    for (int z = 0; z < Z; ++z) s += part[(size_t)z * M * N + i];
    s += bias[col];
    if (TANH) outB[i] = f2bf(tanhf(s));
    else      outF[i] = s;
}

// ---------------- attention: scores + softmax -> P bf16 ----------------
__global__ void __launch_bounds__(256) attn_scores_kernel(const u16* __restrict__ Qb,
        const u16* __restrict__ Kb, u16* __restrict__ P)
{
    __shared__ __align__(16) u16 Ks[304 * 128];   // 77824 B, XOR-swizzled rows
    const int bh = blockIdx.x, b = bh >> 3, h = bh & 7;
    const int tid = threadIdx.x, lane = tid & 63, wid = tid >> 6;
    const int lg = lane >> 4, lr = lane & 15;

    for (int c = tid; c < 304 * 16; c += 256) {
        const int kv = c >> 4, part = c & 15;
        const int tok = b * 300 + imin(kv, 299);
        const short8 v = *(const short8*)(Kb + (size_t)tok * 1024 + h * 128 + part * 8);
        int byte_ = kv * 256 + part * 16;
        byte_ ^= (kv & 7) << 4;
        *(short8*)((char*)Ks + byte_) = v;
    }
    __syncthreads();

    const float scale = 0.08838834764831845f;   // 1/sqrt(128)
    for (int qt = wid; qt < NQT; qt += 4) {
        f32x4 acc[NQT] = {};
        const int qtok = b * 300 + imin(qt * 16 + lr, 299);
        const u16* qrow = Qb + (size_t)qtok * 1024 + h * 128;
        #pragma unroll
        for (int kk = 0; kk < 4; ++kk) {
            const short8 aq = *(const short8*)(qrow + kk * 32 + lg * 8);
            #pragma unroll
            for (int nt = 0; nt < NQT; ++nt) {
                const int kvrow = nt * 16 + lr;
                int byte_ = kvrow * 256 + kk * 64 + lg * 16;
                byte_ ^= (kvrow & 7) << 4;
                const short8 bk = *(const short8*)((char*)Ks + byte_);
                acc[nt] = mfma16(aq, bk, acc[nt]);
            }
        }
        #pragma unroll
        for (int j = 0; j < 4; ++j) {
            float vals[NQT];
            float m = -1e30f;
            #pragma unroll
            for (int nt = 0; nt < NQT; ++nt) {
                float s = acc[nt][j] * scale;
                if (nt * 16 + lr >= 300) s = -1e30f;
                vals[nt] = s;
                m = fmaxf(m, s);
            }
            #pragma unroll
            for (int o = 1; o < 16; o <<= 1) m = fmaxf(m, __shfl_xor(m, o));
            float sum = 0.f;
            #pragma unroll
            for (int nt = 0; nt < NQT; ++nt) { const float e = __expf(vals[nt] - m); vals[nt] = e; sum += e; }
            #pragma unroll
            for (int o = 1; o < 16; o <<= 1) sum += __shfl_xor(sum, o);
            const float inv = 1.0f / sum;
            const int q = qt * 16 + lg * 4 + j;
            if (q < 300) {
                u16* prow = P + ((size_t)bh * 300 + q) * TP;
                #pragma unroll
                for (int nt = 0; nt < NQT; ++nt) prow[nt * 16 + lr] = f2bf(vals[nt] * inv);
                prow[304 + lr] = 0;   // zero kv pad 304..319
            }
        }
    }
}

// ---------------- attention: O = P @ V ----------------
__global__ void __launch_bounds__(256) attn_pv_kernel(const u16* __restrict__ P,
        const u16* __restrict__ Vb, u16* __restrict__ O)
{
    __shared__ __align__(16) u16 Vs[128 * TP];   // V^T, 81920 B, XOR-swizzled rows
    const int bh = blockIdx.x, b = bh >> 3, h = bh & 7;
    const int tid = threadIdx.x, lane = tid & 63, wid = tid >> 6;
    const int lg = lane >> 4, lr = lane & 15;

    for (int c = tid; c < 304 * 16; c += 256) {
        const int kv = c >> 4, dp = c & 15;
        const int tok = b * 300 + imin(kv, 299);
        const short8 v = *(const short8*)(Vb + (size_t)tok * 1024 + h * 128 + dp * 8);
        #pragma unroll
        for (int jj = 0; jj < 8; ++jj) {
            const int d = dp * 8 + jj;
            int byte_ = d * (TP * 2) + kv * 2;
            byte_ ^= (d & 7) << 4;
            *(u16*)((char*)Vs + byte_) = (u16)v[jj];
        }
    }
    for (int c = tid; c < 128 * 16; c += 256) {     // zero kv pad 304..319
        const int d = c >> 4, kv = 304 + (c & 15);
        int byte_ = d * (TP * 2) + kv * 2;
        byte_ ^= (d & 7) << 4;
        *(u16*)((char*)Vs + byte_) = 0;
    }
    __syncthreads();

    for (int qt = wid; qt < NQT; qt += 4) {
        f32x4 acc[8] = {};
        const int q = imin(qt * 16 + lr, 299);
        const u16* prow = P + ((size_t)bh * 300 + q) * TP;
        #pragma unroll
        for (int kk = 0; kk < 10; ++kk) {
            const short8 ap = *(const short8*)(prow + kk * 32 + lg * 8);
            #pragma unroll
            for (int nt = 0; nt < 8; ++nt) {
                const int d = nt * 16 + lr;
                int byte_ = d * (TP * 2) + kk * 64 + lg * 16;
                byte_ ^= (d & 7) << 4;
                const short8 bv8 = *(const short8*)((char*)Vs + byte_);
                acc[nt] = mfma16(ap, bv8, acc[nt]);
            }
        }
        #pragma unroll
        for (int nt = 0; nt < 8; ++nt) {
            #pragma unroll
            for (int j = 0; j < 4; ++j) {
                const int qq = qt * 16 + lg * 4 + j;
                if (qq < 300)
                    O[((size_t)(b * 300 + qq)) * 1024 + h * 128 + nt * 16 + lr] = f2bf(acc[nt][j]);
            }
        }
    }
}

// ---------------- classifier tail ----------------
__global__ void __launch_bounds__(256) logits_kernel(const float* __restrict__ a1,
        const float* __restrict__ cw2, const float* __restrict__ cb2, float* __restrict__ out)
{
    const int tok = blockIdx.x * 4 + (threadIdx.x >> 6);
    const int lane = threadIdx.x & 63;
    if (tok >= NTOK) return;
    const float v0 = a1[(size_t)tok * 128 + lane];
    const float v1 = a1[(size_t)tok * 128 + 64 + lane];
    #pragma unroll
    for (int hp = 0; hp < 4; ++hp) {
        float s = v0 * cw2[lane * 4 + hp] + v1 * cw2[(64 + lane) * 4 + hp];
        #pragma unroll
        for (int o = 1; o < 64; o <<= 1) s += __shfl_xor(s, o);
        if (lane == 0) out[(size_t)tok * 4 + hp] = s + cb2[hp];
    }
}

__global__ void __launch_bounds__(512) softmaxT_kernel(const float* __restrict__ lgt,
        float* __restrict__ alpha, float* __restrict__ outAlpha)
{
    const int bh = blockIdx.x;           // b*4 + hop
    const int b = bh >> 2, hp = bh & 3;
    const int t = threadIdx.x;
    const float v = (t < 300) ? lgt[((size_t)(b * 300 + t)) * 4 + hp] : -1e30f;
    float m = v;
    #pragma unroll
    for (int o = 1; o < 64; o <<= 1) m = fmaxf(m, __shfl_xor(m, o));
    __shared__ float rm[8], rs[8];
    const int lane = t & 63, wid = t >> 6;
    if (lane == 0) rm[wid] = m;
    __syncthreads();
    m = rm[0];
    #pragma unroll
    for (int i = 1; i < 8; ++i) m = fmaxf(m, rm[i]);
    const float e = (t < 300) ? __expf(v - m) : 0.f;
    float s = e;
    #pragma unroll
    for (int o = 1; o < 64; o <<= 1) s += __shfl_xor(s, o);
    if (lane == 0) rs[wid] = s;
    __syncthreads();
    s = rs[0] + rs[1] + rs[2] + rs[3] + rs[4] + rs[5] + rs[6] + rs[7];
    if (t < 300) {
        const float a = e / s;
        alpha[(size_t)bh * 300 + t] = a;
        outAlpha[(size_t)bh * 300 + t] = a;
    }
}

__global__ void __launch_bounds__(256) pool_kernel(const float* __restrict__ alpha,
        const float* __restrict__ xln, float* __restrict__ wsp)
{
    const int bh = blockIdx.x, b = bh >> 2;
    const int d = blockIdx.y * 256 + threadIdx.x;
    const float* xp = xln + (size_t)b * 300 * 1024 + d;
    const float* al = alpha + (size_t)bh * 300;
    float acc = 0.f;
    for (int t = 0; t < 300; ++t) acc += al[t] * xp[(size_t)t * 1024];
    wsp[(size_t)bh * 1024 + d] = acc;
}

// =====================================================================
extern "C" void kernel_launch(void* const* d_in, const int* in_sizes, int n_in,
                              void* d_out, int out_size, void* d_ws, size_t ws_size,
                              hipStream_t stream)
{
    const float* rgb     = (const float*)d_in[0];
    const float* aud     = (const float*)d_in[1];
    const float* embed_W = (const float*)d_in[2];
    const float* embed_b = (const float*)d_in[3];
    const float* Wq      = (const float*)d_in[4];
    const float* bq      = (const float*)d_in[5];
    const float* Wk      = (const float*)d_in[6];
    const float* bk      = (const float*)d_in[7];
    const float* Wv      = (const float*)d_in[8];
    const float* bv      = (const float*)d_in[9];
    const float* Wo      = (const float*)d_in[10];
    const float* bo      = (const float*)d_in[11];
    const float* ln1_a   = (const float*)d_in[12];
    const float* ln1_b   = (const float*)d_in[13];
    const float* W1f     = (const float*)d_in[14];
    const float* b1f     = (const float*)d_in[15];
    const float* W2f     = (const float*)d_in[16];
    const float* b2f     = (const float*)d_in[17];
    const float* ln2_a   = (const float*)d_in[18];
    const float* ln2_b   = (const float*)d_in[19];
    const float* fn_a    = (const float*)d_in[20];
    const float* fn_b    = (const float*)d_in[21];
    const float* cw1     = (const float*)d_in[22];
    const float* cb1     = (const float*)d_in[23];
    const float* cw2     = (const float*)d_in[24];
    const float* cb2     = (const float*)d_in[25];
    const float* cw3     = (const float*)d_in[26];
    const float* cb3     = (const float*)d_in[27];
    const float* cw4     = (const float*)d_in[28];
    const float* cb4     = (const float*)d_in[29];

    char* base = (char*)d_ws;
    size_t off = 0;
    auto alloc = [&](size_t bytes) -> char* {
        char* p = base + off; off += (bytes + 255) & ~(size_t)255; return p; };

    float* x    = (float*)alloc((size_t)NTOK * DD * 4);        // 39.3 MB (c3T aliases after final LN)
    float* pe   = (float*)alloc((size_t)TT * DD * 4);          //  1.2 MB
    u16*  hbuf  = (u16*) alloc((size_t)NTOK * DD * 2);         // 19.7 MB (Ob, splitK partials alias)
    u16*  Qb    = (u16*) alloc((size_t)NTOK * DD * 2);         // 19.7 MB  \ xln aliases Qb+Kb
    u16*  Kb    = (u16*) alloc((size_t)NTOK * DD * 2);         // 19.7 MB  /
    u16*  Vb    = (u16*) alloc((size_t)NTOK * DD * 2);         // 19.7 MB (xlnb aliases)
    u16*  S     = (u16*) alloc((size_t)256 * 300 * TP * 2);    // 49.2 MB shared: feats/pbuf/midc/a1/c4T
    float* lgts = (float*)alloc((size_t)NTOK * 4 * 4);
    float* alph = (float*)alloc((size_t)128 * 300 * 4);
    float* wsp  = (float*)alloc((size_t)32 * 4096 * 4);
    u16*  wsb   = (u16*) alloc((size_t)32 * 4096 * 2);
    u16*  t3b   = (u16*) alloc((size_t)32 * 4096 * 2);
    u16*  eWt   = (u16*) alloc((size_t)1024 * 1152 * 2);       //  2.4 MB
    u16*  WqT   = (u16*) alloc((size_t)1024 * 1024 * 2);       //  2.1 MB (per-layer reuse)
    u16*  WkT   = (u16*) alloc((size_t)1024 * 1024 * 2);
    u16*  WvT   = (u16*) alloc((size_t)1024 * 1024 * 2);
    u16*  WoT   = (u16*) alloc((size_t)1024 * 1024 * 2);
    u16*  W1T   = (u16*) alloc((size_t)DFF * DD * 2);          //  8.4 MB [DFF rows, DD]
    u16*  W2T   = (u16*) alloc((size_t)DD * DFF * 2);          //  8.4 MB [DD rows, DFF]
    u16*  c1T   = (u16*) alloc((size_t)128 * 1024 * 2);
    if (off > ws_size) return;   // ~197.5 MB total; loud failure if insufficient

    u16*  featsb = S;             // 22.1 MB, dead after embed GEMM
    u16*  pbuf   = S;             // 49.2 MB, attn P for all 256 bh (dead outside attn)
    u16*  midc   = S;             // 39.3 MB, FFN half-activation
    u16*  Ob     = hbuf;          // attention output (hbuf dead after QKV gemms)
    float* xln   = (float*)Qb;    // final-LN f32 output: spans Qb+Kb (both dead)
    u16*  xlnb   = Vb;            // final-LN bf16 output (Vb dead)
    float* a1    = (float*)S;     // 4.9 MB, classifier phase
    u16*  c3T    = (u16*)x;       // 32.0 MB  <= 39.3 (x dead after final LN)
    u16*  c4T    = S;             // 31.6 MB  <= 49.2 (written after logits; a1 dead)
    float* part  = (float*)hbuf;  // split-K partials, <=4.1 MB (hbuf dead in classifier)
    float* outv     = (float*)d_out;
    float* outAlpha = outv + (size_t)32 * NCLS;

    const dim3 blk(256);

    pe_kernel<<<(TT * DD + 255) / 256, blk, 0, stream>>>(pe);
    feats_kernel<<<(int)(((size_t)NTOK * FIN + 255) / 256), blk, 0, stream>>>(rgb, aud, featsb);

    auto wconv = [&](const float* W, u16* Wt, int K, int N) {
        dim3 g((N + 31) / 32, (K + 31) / 32);
        wconv_kernel<<<g, dim3(32, 8), 0, stream>>>(W, Wt, K, N);
    };
    wconv(embed_W, eWt, FIN, DD);
    wconv(cw1, c1T, DD, DATT);

    // embed: x = (feats @ W + b)*sqrt(D) + PE   (grid 600 % 8 == 0 -> SWZ)
    gemm_k<EPI_EMBED, 1><<<dim3(8, 75), blk, 0, stream>>>(featsb, eWt, embed_b, pe, x, nullptr,
                                                          NTOK, DD, FIN, FIN, FIN, 0);

    for (int i = 0; i < 4; ++i) {
        wconv(Wq  + (size_t)i * DD * DD,  WqT, DD, DD);
        wconv(Wk  + (size_t)i * DD * DD,  WkT, DD, DD);
        wconv(Wv  + (size_t)i * DD * DD,  WvT, DD, DD);
        wconv(Wo  + (size_t)i * DD * DD,  WoT, DD, DD);
        wconv(W1f + (size_t)i * DD * DFF, W1T, DD, DFF);
        wconv(W2f + (size_t)i * DFF * DD, W2T, DFF, DD);

        ln_kernel<0><<<NTOK, blk, 0, stream>>>(x, ln1_a + (size_t)i * DD, ln1_b + (size_t)i * DD, hbuf, nullptr);
        gemm_k<EPI_B_BF16, 1><<<dim3(8, 75), blk, 0, stream>>>(hbuf, WqT, bq + (size_t)i * DD, nullptr, nullptr, Qb,
                                                               NTOK, DD, DD, DD, DD, 0);
        gemm_k<EPI_B_BF16, 1><<<dim3(8, 75), blk, 0, stream>>>(hbuf, WkT, bk + (size_t)i * DD, nullptr, nullptr, Kb,
                                                               NTOK, DD, DD, DD, DD, 0);
        gemm_k<EPI_B_BF16, 1><<<dim3(8, 75), blk, 0, stream>>>(hbuf, WvT, bv + (size_t)i * DD, nullptr, nullptr, Vb,
                                                               NTOK, DD, DD, DD, DD, 0);
        attn_scores_kernel<<<256, blk, 0, stream>>>(Qb, Kb, pbuf);
        attn_pv_kernel<<<256, blk, 0, stream>>>(pbuf, Vb, Ob);      // Ob = hbuf (dead now)
        gemm_k<EPI_B_RES_F32, 1><<<dim3(8, 75), blk, 0, stream>>>(Ob, WoT, bo + (size_t)i * DD, x, x, nullptr,
                                                                  NTOK, DD, DD, DD, DD, 0);
        ln_kernel<0><<<NTOK, blk, 0, stream>>>(x, ln2_a + (size_t)i * DD, ln2_b + (size_t)i * DD, hbuf, nullptr);
        // FFN split over DFF halves: midc holds [9600, 2048]
        for (int h = 0; h < 2; ++h) {
            gemm_k<EPI_B_RELU_BF16, 1><<<dim3(16, 75), blk, 0, stream>>>(hbuf, W1T + (size_t)h * 2048 * DD,
                    b1f + (size_t)i * DFF + h * 2048, nullptr, nullptr, midc,
                    NTOK, 2048, DD, DD, DD, 0);
            if (h == 0)
                gemm_k<EPI_B_RES_F32, 1><<<dim3(8, 75), blk, 0, stream>>>(midc, W2T + (size_t)h * 2048,
                        b2f + (size_t)i * DD, x, x, nullptr, NTOK, DD, 2048, 2048, DFF, 0);
            else
                gemm_k<EPI_ACC_F32, 1><<<dim3(8, 75), blk, 0, stream>>>(midc, W2T + (size_t)h * 2048,
                        b2f + (size_t)i * DD, x, x, nullptr, NTOK, DD, 2048, 2048, DFF, 0);
        }
    }

    ln_kernel<1><<<NTOK, blk, 0, stream>>>(x, fn_a, fn_b, xlnb, xln);
    wconv(cw3, c3T, 4096, DFF);                               // x dead -> c3T
    gemm_k<EPI_B_TANH_F32, 0><<<dim3(1, 75), blk, 0, stream>>>(xlnb, c1T, cb1, nullptr, a1, nullptr,
                                                               NTOK, DATT, DD, DD, DD, 0);
    logits_kernel<<<2400, blk, 0, stream>>>(a1, cw2, cb2, lgts);
    wconv(cw4, c4T, DFF, NCLS);                               // a1 dead -> c4T
    softmaxT_kernel<<<128, dim3(512), 0, stream>>>(lgts, alph, outAlpha);
    pool_kernel<<<dim3(128, 4), blk, 0, stream>>>(alph, xln, wsp);
    f2bf_kernel<<<(32 * 4096 + 255) / 256, blk, 0, stream>>>(wsp, wsb, 32 * 4096);

    // classifier GEMMs: split-K (Z=8, Kc=512), deterministic reduce
    gemm_k<EPI_PART, 0><<<dim3(32, 1, 8), blk, 0, stream>>>(wsb, c3T, nullptr, nullptr, part, nullptr,
                                                            32, 4096, 4096, 4096, 4096, 512);
    redk_kernel<1><<<(32 * 4096 + 255) / 256, blk, 0, stream>>>(part, cb3, nullptr, t3b, 32, 4096, 8);
    gemm_k<EPI_PART, 0><<<dim3(31, 1, 8), blk, 0, stream>>>(t3b, c4T, nullptr, nullptr, part, nullptr,
                                                            32, NCLS, 4096, 4096, 4096, 512);
    redk_kernel<0><<<(32 * NCLS + 255) / 256, blk, 0, stream>>>(part, cb4, outv, nullptr, 32, NCLS, 8);
}

// Round 5
// 2629.957 us; speedup vs baseline: 1.6545x; 1.0294x over previous
//
#include <hip/hip_runtime.h>
#include <stdint.h>

#define NTOK 9600
#define TT   300
#define DD   1024
#define HH   8
#define DFF  4096
#define FIN  1152
#define DATT 128
#define NCLS 3862
#define TP   320   // kv padded for PV k-steps
#define NQT  19    // ceil(304/16) tiles of 16

typedef unsigned short u16;
typedef __attribute__((ext_vector_type(8))) short short8;
typedef __attribute__((ext_vector_type(4))) float f32x4;

__device__ __forceinline__ int imin(int a, int b){ return a < b ? a : b; }

__device__ __forceinline__ u16 f2bf(float f){
    union { float f; uint32_t u; } v; v.f = f;
    uint32_t u = v.u;
    return (u16)((u + 0x7fffu + ((u >> 16) & 1u)) >> 16);
}

__device__ __forceinline__ f32x4 mfma16(short8 a, short8 b, f32x4 c){
    return __builtin_amdgcn_mfma_f32_16x16x32_bf16(a, b, c, 0, 0, 0);
}

// async global->LDS, 16B per lane. LDS dest must be wave-uniform base + lane*16 (linear).
__device__ __forceinline__ void gll16(const void* g, void* l){
    __builtin_amdgcn_global_load_lds((const __attribute__((address_space(1))) void*)g,
                                     (__attribute__((address_space(3))) void*)l, 16, 0, 0);
}

// ---------------- PE table ----------------
__global__ void __launch_bounds__(256) pe_kernel(float* __restrict__ pe)
{
    const int i = blockIdx.x * 256 + threadIdx.x;
    if (i >= TT * DD) return;
    const int t = i >> 10, d = i & 1023;
    const float fr = expf(-(float)(d & ~1) * (9.210340371976184f / 1024.0f));
    const float ang = (float)t * fr;
    pe[i] = (d & 1) ? cosf(ang) : sinf(ang);
}

// ---------------- feats concat + /255 -> bf16 ----------------
__global__ void __launch_bounds__(256) feats_kernel(const float* __restrict__ rgb,
        const float* __restrict__ aud, u16* __restrict__ out)
{
    const long i = (long)blockIdx.x * 256 + threadIdx.x;
    if (i >= (long)NTOK * FIN) return;
    const int row = (int)(i / FIN), c = (int)(i % FIN);
    const float v = (c < 1024) ? rgb[(size_t)row * 1024 + c] : aud[(size_t)row * 128 + (c - 1024)];
    out[i] = f2bf(v * (1.0f / 255.0f));
}

// ---------------- weight transpose + convert: W[K,N] f32 -> Wt[N,K] bf16 ----------------
__global__ void __launch_bounds__(256) wconv_kernel(const float* __restrict__ W,
        u16* __restrict__ Wt, int K, int N)
{
    __shared__ float tile[32][33];
    const int k0 = blockIdx.y * 32, n0 = blockIdx.x * 32;
    const int tx = threadIdx.x, ty = threadIdx.y;   // 32 x 8
    #pragma unroll
    for (int i = 0; i < 4; ++i) {
        const int k = k0 + ty + i * 8, n = n0 + tx;
        tile[ty + i * 8][tx] = (k < K && n < N) ? W[(size_t)k * N + n] : 0.f;
    }
    __syncthreads();
    #pragma unroll
    for (int i = 0; i < 4; ++i) {
        const int n = n0 + ty + i * 8, k = k0 + tx;
        if (n < N && k < K) Wt[(size_t)n * K + k] = f2bf(tile[tx][ty + i * 8]);
    }
}

// ---------------- f32 -> bf16 ----------------
__global__ void __launch_bounds__(256) f2bf_kernel(const float* __restrict__ in,
        u16* __restrict__ out, int n)
{
    const int i = blockIdx.x * 256 + threadIdx.x;
    if (i < n) out[i] = f2bf(in[i]);
}

// ---------------- fused QKV bias gather: [4][3072] ----------------
__global__ void __launch_bounds__(256) qkvbias_kernel(const float* __restrict__ bq,
        const float* __restrict__ bk, const float* __restrict__ bv, float* __restrict__ out)
{
    const int i = blockIdx.x * 256 + threadIdx.x;
    if (i >= 4 * 3072) return;
    const int l = i / 3072, c = i % 3072;
    float v;
    if      (c < 1024) v = bq[l * 1024 + c];
    else if (c < 2048) v = bk[l * 1024 + c - 1024];
    else               v = bv[l * 1024 + c - 2048];
    out[i] = v;
}

// ---------------- LayerNorm (ddof=1, a*(x-m)/(std+eps)+b) ----------------
template<int WF>
__global__ void __launch_bounds__(256) ln_kernel(const float* __restrict__ xin,
        const float* __restrict__ ga, const float* __restrict__ gb,
        u16* __restrict__ ob, float* of)
{
    const int row = blockIdx.x, t = threadIdx.x;
    const float4 xv = *(const float4*)(xin + (size_t)row * 1024 + t * 4);
    float s1 = xv.x + xv.y + xv.z + xv.w;
    float s2 = xv.x * xv.x + xv.y * xv.y + xv.z * xv.z + xv.w * xv.w;
    #pragma unroll
    for (int o = 1; o < 64; o <<= 1) { s1 += __shfl_xor(s1, o); s2 += __shfl_xor(s2, o); }
    __shared__ float r1[4], r2[4];
    const int lane = t & 63, wid = t >> 6;
    if (lane == 0) { r1[wid] = s1; r2[wid] = s2; }
    __syncthreads();
    s1 = r1[0] + r1[1] + r1[2] + r1[3];
    s2 = r2[0] + r2[1] + r2[2] + r2[3];
    const float mean = s1 * (1.0f / 1024.0f);
    const float var  = (s2 - 1024.0f * mean * mean) * (1.0f / 1023.0f);
    const float inv  = 1.0f / (sqrtf(fmaxf(var, 0.f)) + 1e-6f);
    const float4 av  = *(const float4*)(ga + t * 4);
    const float4 bv  = *(const float4*)(gb + t * 4);
    const float y0 = av.x * (xv.x - mean) * inv + bv.x;
    const float y1 = av.y * (xv.y - mean) * inv + bv.y;
    const float y2 = av.z * (xv.z - mean) * inv + bv.z;
    const float y3 = av.w * (xv.w - mean) * inv + bv.w;
    ushort4 o4; o4.x = f2bf(y0); o4.y = f2bf(y1); o4.z = f2bf(y2); o4.w = f2bf(y3);
    *(ushort4*)(ob + (size_t)row * 1024 + t * 4) = o4;
    if (WF) {
        float4 yo; yo.x = y0; yo.y = y1; yo.z = y2; yo.w = y3;
        *(float4*)(of + (size_t)row * 1024 + t * 4) = yo;
    }
}

// ---------------- epilogue codes ----------------
#define EPI_EMBED        0
#define EPI_QKV          1   // route col>>10 to outB/outB2/outB3 (stride 1024)
#define EPI_B_RELU_BF16  2
#define EPI_B_RES_F32    3
#define EPI_B_TANH_F32   4
#define EPI_ACC_F32      5   // outF = v + extra (no bias; FFN2 second half)
#define EPI_PART         6   // partials for split-K: outF[z*M*N + oi] = v

// ---- generic bf16 MFMA GEMM: C = A[M,K] * Bt[N,K]^T ----
// 2-phase double-buffered global_load_lds staging (T3 minimum recipe).
// SWZ=1: XCD-aware block remap (T1); requires grid.x*grid.y % 8 == 0.
template<int EPI, int SWZ>
__global__ void __launch_bounds__(256) gemm_k(const u16* __restrict__ A, const u16* __restrict__ Bt,
        const float* __restrict__ bias, const float* extra,
        float* outF, u16* outB, u16* outB2, u16* outB3, int M, int N, int K,
        int lda, int ldb, int kchunk)
{
    __shared__ __align__(16) u16 As[2][4096];
    __shared__ __align__(16) u16 Bs[2][4096];
    const int tid = threadIdx.x;
    int bm, bn;
    if (SWZ) {
        int lin = blockIdx.y * gridDim.x + blockIdx.x;
        const int nwg = gridDim.x * gridDim.y;
        const int cpx = nwg >> 3;
        lin = (lin & 7) * cpx + (lin >> 3);
        bm = lin / gridDim.x;
        bn = lin - bm * gridDim.x;
    } else {
        bm = blockIdx.y; bn = blockIdx.x;
    }
    const int lane = tid & 63, wid = tid >> 6;
    const int lg = lane >> 4, lr = lane & 15;
    const int wr = wid >> 1, wc = wid & 1;

    int koff = 0, Keff = K;
    if (kchunk > 0) { koff = blockIdx.z * kchunk; Keff = kchunk; }

    const int srow = tid >> 2;
    const int skc  = (tid & 3) * 8;
    const u16* ap0 = A  + (size_t)imin(bm * 128 + srow,      M - 1) * lda + skc + koff;
    const u16* ap1 = A  + (size_t)imin(bm * 128 + srow + 64, M - 1) * lda + skc + koff;
    const u16* bp0 = Bt + (size_t)imin(bn * 128 + srow,      N - 1) * ldb + skc + koff;
    const u16* bp1 = Bt + (size_t)imin(bn * 128 + srow + 64, N - 1) * ldb + skc + koff;

    f32x4 acc[4][4] = {};

    auto STAGE = [&](int b, int k0) {
        gll16(ap0 + k0, &As[b][tid * 8]);
        gll16(ap1 + k0, &As[b][2048 + tid * 8]);
        gll16(bp0 + k0, &Bs[b][tid * 8]);
        gll16(bp1 + k0, &Bs[b][2048 + tid * 8]);
    };
    auto COMPUTE = [&](int b) {
        short8 af[4], bf[4];
        #pragma unroll
        for (int m = 0; m < 4; ++m)
            af[m] = *(const short8*)(&As[b][(wr * 64 + m * 16 + lr) * 32 + lg * 8]);
        #pragma unroll
        for (int n = 0; n < 4; ++n)
            bf[n] = *(const short8*)(&Bs[b][(wc * 64 + n * 16 + lr) * 32 + lg * 8]);
        #pragma unroll
        for (int m = 0; m < 4; ++m)
            #pragma unroll
            for (int n = 0; n < 4; ++n)
                acc[m][n] = mfma16(af[m], bf[n], acc[m][n]);
    };

    STAGE(0, 0);
    __syncthreads();                       // buf0 staged (full vmcnt drain at barrier)
    int cur = 0;
    for (int k0 = 32; k0 < Keff; k0 += 32) {
        STAGE(cur ^ 1, k0);                // next tile in flight during compute
        COMPUTE(cur);
        __syncthreads();                   // drains stage + all LDS reads of buf[cur]
        cur ^= 1;
    }
    COMPUTE(cur);                          // last tile

    #pragma unroll
    for (int m = 0; m < 4; ++m) {
        const int rb = bm * 128 + wr * 64 + m * 16 + lg * 4;
        #pragma unroll
        for (int n = 0; n < 4; ++n) {
            const int col = bn * 128 + wc * 64 + n * 16 + lr;
            if (col >= N) continue;
            const float bvl = (EPI == EPI_PART || EPI == EPI_ACC_F32) ? 0.f : bias[col];
            #pragma unroll
            for (int j = 0; j < 4; ++j) {
                const int r = rb + j;
                if (r >= M) continue;
                const float v = acc[m][n][j];
                const size_t oi = (size_t)r * N + col;
                if      (EPI == EPI_EMBED)       outF[oi] = (v + bvl) * 32.0f + extra[(size_t)(r % 300) * 1024 + col];
                else if (EPI == EPI_QKV) {
                    const int q = col >> 10, lc = col & 1023;
                    u16* dst = (q == 0) ? outB : ((q == 1) ? outB2 : outB3);
                    dst[(size_t)r * 1024 + lc] = f2bf(v + bvl);
                }
                else if (EPI == EPI_B_RELU_BF16) outB[oi] = f2bf(fmaxf(v + bvl, 0.f));
                else if (EPI == EPI_B_RES_F32)   outF[oi] = v + bvl + extra[oi];
                else if (EPI == EPI_B_TANH_F32)  outF[oi] = tanhf(v + bvl);
                else if (EPI == EPI_ACC_F32)     outF[oi] = v + extra[oi];
                else if (EPI == EPI_PART)        outF[(size_t)blockIdx.z * M * N + oi] = v;
            }
        }
    }
}

// ---------------- split-K reduce + bias (+tanh) ----------------
template<int TANH>
__global__ void __launch_bounds__(256) redk_kernel(const float* __restrict__ part,
        const float* __restrict__ bias, float* outF, u16* outB, int M, int N, int Z)
{
    const int i = blockIdx.x * 256 + threadIdx.x;
    if (i >= M * N) return;
    const int col = i % N;
    float s = 0.f;
    for (int z = 0; z < Z; ++z) s += part[(size_t)z * M * N + i];
    s += bias[col];
    if (TANH) outB[i] = f2bf(tanhf(s));
    else      outF[i] = s;
}

// ---------------- attention: scores + softmax -> P bf16 ----------------
__global__ void __launch_bounds__(256) attn_scores_kernel(const u16* __restrict__ Qb,
        const u16* __restrict__ Kb, u16* __restrict__ P)
{
    __shared__ __align__(16) u16 Ks[304 * 128];   // 77824 B, XOR-swizzled rows
    const int bh = blockIdx.x, b = bh >> 3, h = bh & 7;
    const int tid = threadIdx.x, lane = tid & 63, wid = tid >> 6;
    const int lg = lane >> 4, lr = lane & 15;

    for (int c = tid; c < 304 * 16; c += 256) {
        const int kv = c >> 4, part = c & 15;
        const int tok = b * 300 + imin(kv, 299);
        const short8 v = *(const short8*)(Kb + (size_t)tok * 1024 + h * 128 + part * 8);
        int byte_ = kv * 256 + part * 16;
        byte_ ^= (kv & 7) << 4;
        *(short8*)((char*)Ks + byte_) = v;
    }
    __syncthreads();

    const float scale = 0.08838834764831845f;   // 1/sqrt(128)
    for (int qt = wid; qt < NQT; qt += 4) {
        f32x4 acc[NQT] = {};
        const int qtok = b * 300 + imin(qt * 16 + lr, 299);
        const u16* qrow = Qb + (size_t)qtok * 1024 + h * 128;
        #pragma unroll
        for (int kk = 0; kk < 4; ++kk) {
            const short8 aq = *(const short8*)(qrow + kk * 32 + lg * 8);
            #pragma unroll
            for (int nt = 0; nt < NQT; ++nt) {
                const int kvrow = nt * 16 + lr;
                int byte_ = kvrow * 256 + kk * 64 + lg * 16;
                byte_ ^= (kvrow & 7) << 4;
                const short8 bk = *(const short8*)((char*)Ks + byte_);
                acc[nt] = mfma16(aq, bk, acc[nt]);
            }
        }
        #pragma unroll
        for (int j = 0; j < 4; ++j) {
            float vals[NQT];
            float m = -1e30f;
            #pragma unroll
            for (int nt = 0; nt < NQT; ++nt) {
                float s = acc[nt][j] * scale;
                if (nt * 16 + lr >= 300) s = -1e30f;
                vals[nt] = s;
                m = fmaxf(m, s);
            }
            #pragma unroll
            for (int o = 1; o < 16; o <<= 1) m = fmaxf(m, __shfl_xor(m, o));
            float sum = 0.f;
            #pragma unroll
            for (int nt = 0; nt < NQT; ++nt) { const float e = __expf(vals[nt] - m); vals[nt] = e; sum += e; }
            #pragma unroll
            for (int o = 1; o < 16; o <<= 1) sum += __shfl_xor(sum, o);
            const float inv = 1.0f / sum;
            const int q = qt * 16 + lg * 4 + j;
            if (q < 300) {
                u16* prow = P + ((size_t)bh * 300 + q) * TP;
                #pragma unroll
                for (int nt = 0; nt < NQT; ++nt) prow[nt * 16 + lr] = f2bf(vals[nt] * inv);
                prow[304 + lr] = 0;   // zero kv pad 304..319
            }
        }
    }
}

// ---------------- attention: O = P @ V ----------------
__global__ void __launch_bounds__(256) attn_pv_kernel(const u16* __restrict__ P,
        const u16* __restrict__ Vb, u16* __restrict__ O)
{
    __shared__ __align__(16) u16 Vs[128 * TP];   // V^T, 81920 B, XOR-swizzled rows
    const int bh = blockIdx.x, b = bh >> 3, h = bh & 7;
    const int tid = threadIdx.x, lane = tid & 63, wid = tid >> 6;
    const int lg = lane >> 4, lr = lane & 15;

    for (int c = tid; c < 304 * 16; c += 256) {
        const int kv = c >> 4, dp = c & 15;
        const int tok = b * 300 + imin(kv, 299);
        const short8 v = *(const short8*)(Vb + (size_t)tok * 1024 + h * 128 + dp * 8);
        #pragma unroll
        for (int jj = 0; jj < 8; ++jj) {
            const int d = dp * 8 + jj;
            int byte_ = d * (TP * 2) + kv * 2;
            byte_ ^= (d & 7) << 4;
            *(u16*)((char*)Vs + byte_) = (u16)v[jj];
        }
    }
    for (int c = tid; c < 128 * 16; c += 256) {     // zero kv pad 304..319
        const int d = c >> 4, kv = 304 + (c & 15);
        int byte_ = d * (TP * 2) + kv * 2;
        byte_ ^= (d & 7) << 4;
        *(u16*)((char*)Vs + byte_) = 0;
    }
    __syncthreads();

    for (int qt = wid; qt < NQT; qt += 4) {
        f32x4 acc[8] = {};
        const int q = imin(qt * 16 + lr, 299);
        const u16* prow = P + ((size_t)bh * 300 + q) * TP;
        #pragma unroll
        for (int kk = 0; kk < 10; ++kk) {
            const short8 ap = *(const short8*)(prow + kk * 32 + lg * 8);
            #pragma unroll
            for (int nt = 0; nt < 8; ++nt) {
                const int d = nt * 16 + lr;
                int byte_ = d * (TP * 2) + kk * 64 + lg * 16;
                byte_ ^= (d & 7) << 4;
                const short8 bv8 = *(const short8*)((char*)Vs + byte_);
                acc[nt] = mfma16(ap, bv8, acc[nt]);
            }
        }
        #pragma unroll
        for (int nt = 0; nt < 8; ++nt) {
            #pragma unroll
            for (int j = 0; j < 4; ++j) {
                const int qq = qt * 16 + lg * 4 + j;
                if (qq < 300)
                    O[((size_t)(b * 300 + qq)) * 1024 + h * 128 + nt * 16 + lr] = f2bf(acc[nt][j]);
            }
        }
    }
}

// ---------------- classifier tail ----------------
__global__ void __launch_bounds__(256) logits_kernel(const float* __restrict__ a1,
        const float* __restrict__ cw2, const float* __restrict__ cb2, float* __restrict__ out)
{
    const int tok = blockIdx.x * 4 + (threadIdx.x >> 6);
    const int lane = threadIdx.x & 63;
    if (tok >= NTOK) return;
    const float v0 = a1[(size_t)tok * 128 + lane];
    const float v1 = a1[(size_t)tok * 128 + 64 + lane];
    #pragma unroll
    for (int hp = 0; hp < 4; ++hp) {
        float s = v0 * cw2[lane * 4 + hp] + v1 * cw2[(64 + lane) * 4 + hp];
        #pragma unroll
        for (int o = 1; o < 64; o <<= 1) s += __shfl_xor(s, o);
        if (lane == 0) out[(size_t)tok * 4 + hp] = s + cb2[hp];
    }
}

__global__ void __launch_bounds__(512) softmaxT_kernel(const float* __restrict__ lgt,
        float* __restrict__ alpha, float* __restrict__ outAlpha)
{
    const int bh = blockIdx.x;           // b*4 + hop
    const int b = bh >> 2, hp = bh & 3;
    const int t = threadIdx.x;
    const float v = (t < 300) ? lgt[((size_t)(b * 300 + t)) * 4 + hp] : -1e30f;
    float m = v;
    #pragma unroll
    for (int o = 1; o < 64; o <<= 1) m = fmaxf(m, __shfl_xor(m, o));
    __shared__ float rm[8], rs[8];
    const int lane = t & 63, wid = t >> 6;
    if (lane == 0) rm[wid] = m;
    __syncthreads();
    m = rm[0];
    #pragma unroll
    for (int i = 1; i < 8; ++i) m = fmaxf(m, rm[i]);
    const float e = (t < 300) ? __expf(v - m) : 0.f;
    float s = e;
    #pragma unroll
    for (int o = 1; o < 64; o <<= 1) s += __shfl_xor(s, o);
    if (lane == 0) rs[wid] = s;
    __syncthreads();
    s = rs[0] + rs[1] + rs[2] + rs[3] + rs[4] + rs[5] + rs[6] + rs[7];
    if (t < 300) {
        const float a = e / s;
        alpha[(size_t)bh * 300 + t] = a;
        outAlpha[(size_t)bh * 300 + t] = a;
    }
}

__global__ void __launch_bounds__(256) pool_kernel(const float* __restrict__ alpha,
        const float* __restrict__ xln, float* __restrict__ wsp)
{
    const int bh = blockIdx.x, b = bh >> 2;
    const int d = blockIdx.y * 256 + threadIdx.x;
    const float* xp = xln + (size_t)b * 300 * 1024 + d;
    const float* al = alpha + (size_t)bh * 300;
    float acc = 0.f;
    for (int t = 0; t < 300; ++t) acc += al[t] * xp[(size_t)t * 1024];
    wsp[(size_t)bh * 1024 + d] = acc;
}

// =====================================================================
extern "C" void kernel_launch(void* const* d_in, const int* in_sizes, int n_in,
                              void* d_out, int out_size, void* d_ws, size_t ws_size,
                              hipStream_t stream)
{
    const float* rgb     = (const float*)d_in[0];
    const float* aud     = (const float*)d_in[1];
    const float* embed_W = (const float*)d_in[2];
    const float* embed_b = (const float*)d_in[3];
    const float* Wq      = (const float*)d_in[4];
    const float* bq      = (const float*)d_in[5];
    const float* Wk      = (const float*)d_in[6];
    const float* bk      = (const float*)d_in[7];
    const float* Wv      = (const float*)d_in[8];
    const float* bv      = (const float*)d_in[9];
    const float* Wo      = (const float*)d_in[10];
    const float* bo      = (const float*)d_in[11];
    const float* ln1_a   = (const float*)d_in[12];
    const float* ln1_b   = (const float*)d_in[13];
    const float* W1f     = (const float*)d_in[14];
    const float* b1f     = (const float*)d_in[15];
    const float* W2f     = (const float*)d_in[16];
    const float* b2f     = (const float*)d_in[17];
    const float* ln2_a   = (const float*)d_in[18];
    const float* ln2_b   = (const float*)d_in[19];
    const float* fn_a    = (const float*)d_in[20];
    const float* fn_b    = (const float*)d_in[21];
    const float* cw1     = (const float*)d_in[22];
    const float* cb1     = (const float*)d_in[23];
    const float* cw2     = (const float*)d_in[24];
    const float* cb2     = (const float*)d_in[25];
    const float* cw3     = (const float*)d_in[26];
    const float* cb3     = (const float*)d_in[27];
    const float* cw4     = (const float*)d_in[28];
    const float* cb4     = (const float*)d_in[29];

    char* base = (char*)d_ws;
    size_t off = 0;
    auto alloc = [&](size_t bytes) -> char* {
        char* p = base + off; off += (bytes + 255) & ~(size_t)255; return p; };

    float* x    = (float*)alloc((size_t)NTOK * DD * 4);        // 39.3 MB (c3T aliases after final LN)
    float* pe   = (float*)alloc((size_t)TT * DD * 4);          //  1.2 MB
    u16*  hbuf  = (u16*) alloc((size_t)NTOK * DD * 2);         // 19.7 MB (Ob, splitK partials alias)
    u16*  Qb    = (u16*) alloc((size_t)NTOK * DD * 2);         // 19.7 MB  \ xln aliases Qb+Kb
    u16*  Kb    = (u16*) alloc((size_t)NTOK * DD * 2);         // 19.7 MB  /
    u16*  Vb    = (u16*) alloc((size_t)NTOK * DD * 2);         // 19.7 MB (xlnb aliases)
    u16*  S     = (u16*) alloc((size_t)256 * 300 * TP * 2);    // 49.2 MB shared: feats/pbuf/midc/a1/c4T
    float* lgts = (float*)alloc((size_t)NTOK * 4 * 4);
    float* alph = (float*)alloc((size_t)128 * 300 * 4);
    float* wsp  = (float*)alloc((size_t)32 * 4096 * 4);
    u16*  wsb   = (u16*) alloc((size_t)32 * 4096 * 2);
    u16*  t3b   = (u16*) alloc((size_t)32 * 4096 * 2);
    float* bqkv = (float*)alloc((size_t)4 * 3072 * 4);         // fused QKV bias
    u16*  eWt   = (u16*) alloc((size_t)1024 * 1152 * 2);       //  2.4 MB
    u16*  WqkvT = (u16*) alloc((size_t)3 * 1024 * 1024 * 2);   //  6.3 MB (fused, per-layer reuse)
    u16*  WoT   = (u16*) alloc((size_t)1024 * 1024 * 2);
    u16*  W1T   = (u16*) alloc((size_t)DFF * DD * 2);          //  8.4 MB [DFF rows, DD]
    u16*  W2T   = (u16*) alloc((size_t)DD * DFF * 2);          //  8.4 MB [DD rows, DFF]
    u16*  c1T   = (u16*) alloc((size_t)128 * 1024 * 2);
    if (off > ws_size) return;   // ~197.6 MB total; loud failure if insufficient

    u16*  featsb = S;             // 22.1 MB, dead after embed GEMM
    u16*  pbuf   = S;             // 49.2 MB, attn P for all 256 bh (dead outside attn)
    u16*  midc   = S;             // 39.3 MB, FFN half-activation
    u16*  Ob     = hbuf;          // attention output (hbuf dead after QKV gemm)
    float* xln   = (float*)Qb;    // final-LN f32 output: spans Qb+Kb (both dead)
    u16*  xlnb   = Vb;            // final-LN bf16 output (Vb dead)
    float* a1    = (float*)S;     // 4.9 MB, classifier phase
    u16*  c3T    = (u16*)x;       // 32.0 MB  <= 39.3 (x dead after final LN)
    u16*  c4T    = S;             // 31.6 MB  <= 49.2 (written after logits; a1 dead)
    float* part  = (float*)hbuf;  // split-K partials, <=4.1 MB (hbuf dead in classifier)
    float* outv     = (float*)d_out;
    float* outAlpha = outv + (size_t)32 * NCLS;

    const dim3 blk(256);

    pe_kernel<<<(TT * DD + 255) / 256, blk, 0, stream>>>(pe);
    feats_kernel<<<(int)(((size_t)NTOK * FIN + 255) / 256), blk, 0, stream>>>(rgb, aud, featsb);
    qkvbias_kernel<<<(4 * 3072 + 255) / 256, blk, 0, stream>>>(bq, bk, bv, bqkv);

    auto wconv = [&](const float* W, u16* Wt, int K, int N) {
        dim3 g((N + 31) / 32, (K + 31) / 32);
        wconv_kernel<<<g, dim3(32, 8), 0, stream>>>(W, Wt, K, N);
    };
    wconv(embed_W, eWt, FIN, DD);
    wconv(cw1, c1T, DD, DATT);

    // embed: x = (feats @ W + b)*sqrt(D) + PE   (grid 600 % 8 == 0 -> SWZ)
    gemm_k<EPI_EMBED, 1><<<dim3(8, 75), blk, 0, stream>>>(featsb, eWt, embed_b, pe, x,
            nullptr, nullptr, nullptr, NTOK, DD, FIN, FIN, FIN, 0);

    for (int i = 0; i < 4; ++i) {
        wconv(Wq  + (size_t)i * DD * DD,  WqkvT,                 DD, DD);
        wconv(Wk  + (size_t)i * DD * DD,  WqkvT + 1024 * 1024,   DD, DD);
        wconv(Wv  + (size_t)i * DD * DD,  WqkvT + 2 * 1024 * 1024, DD, DD);
        wconv(Wo  + (size_t)i * DD * DD,  WoT, DD, DD);
        wconv(W1f + (size_t)i * DD * DFF, W1T, DD, DFF);
        wconv(W2f + (size_t)i * DFF * DD, W2T, DFF, DD);

        ln_kernel<0><<<NTOK, blk, 0, stream>>>(x, ln1_a + (size_t)i * DD, ln1_b + (size_t)i * DD, hbuf, nullptr);
        // fused QKV: N = 3072, grid 1800 % 8 == 0
        gemm_k<EPI_QKV, 1><<<dim3(24, 75), blk, 0, stream>>>(hbuf, WqkvT, bqkv + (size_t)i * 3072, nullptr,
                nullptr, Qb, Kb, Vb, NTOK, 3072, DD, DD, DD, 0);
        attn_scores_kernel<<<256, blk, 0, stream>>>(Qb, Kb, pbuf);
        attn_pv_kernel<<<256, blk, 0, stream>>>(pbuf, Vb, Ob);      // Ob = hbuf (dead now)
        gemm_k<EPI_B_RES_F32, 1><<<dim3(8, 75), blk, 0, stream>>>(Ob, WoT, bo + (size_t)i * DD, x, x,
                nullptr, nullptr, nullptr, NTOK, DD, DD, DD, DD, 0);
        ln_kernel<0><<<NTOK, blk, 0, stream>>>(x, ln2_a + (size_t)i * DD, ln2_b + (size_t)i * DD, hbuf, nullptr);
        // FFN split over DFF halves: midc holds [9600, 2048]
        for (int h = 0; h < 2; ++h) {
            gemm_k<EPI_B_RELU_BF16, 1><<<dim3(16, 75), blk, 0, stream>>>(hbuf, W1T + (size_t)h * 2048 * DD,
                    b1f + (size_t)i * DFF + h * 2048, nullptr, nullptr, midc, nullptr, nullptr,
                    NTOK, 2048, DD, DD, DD, 0);
            if (h == 0)
                gemm_k<EPI_B_RES_F32, 1><<<dim3(8, 75), blk, 0, stream>>>(midc, W2T + (size_t)h * 2048,
                        b2f + (size_t)i * DD, x, x, nullptr, nullptr, nullptr, NTOK, DD, 2048, 2048, DFF, 0);
            else
                gemm_k<EPI_ACC_F32, 1><<<dim3(8, 75), blk, 0, stream>>>(midc, W2T + (size_t)h * 2048,
                        b2f + (size_t)i * DD, x, x, nullptr, nullptr, nullptr, NTOK, DD, 2048, 2048, DFF, 0);
        }
    }

    ln_kernel<1><<<NTOK, blk, 0, stream>>>(x, fn_a, fn_b, xlnb, xln);
    wconv(cw3, c3T, 4096, DFF);                               // x dead -> c3T
    gemm_k<EPI_B_TANH_F32, 0><<<dim3(1, 75), blk, 0, stream>>>(xlnb, c1T, cb1, nullptr, a1,
            nullptr, nullptr, nullptr, NTOK, DATT, DD, DD, DD, 0);
    logits_kernel<<<2400, blk, 0, stream>>>(a1, cw2, cb2, lgts);
    wconv(cw4, c4T, DFF, NCLS);                               // a1 dead -> c4T
    softmaxT_kernel<<<128, dim3(512), 0, stream>>>(lgts, alph, outAlpha);
    pool_kernel<<<dim3(128, 4), blk, 0, stream>>>(alph, xln, wsp);
    f2bf_kernel<<<(32 * 4096 + 255) / 256, blk, 0, stream>>>(wsp, wsb, 32 * 4096);

    // classifier GEMMs: split-K (Z=8, Kc=512), deterministic reduce
    gemm_k<EPI_PART, 0><<<dim3(32, 1, 8), blk, 0, stream>>>(wsb, c3T, nullptr, nullptr, part,
            nullptr, nullptr, nullptr, 32, 4096, 4096, 4096, 4096, 512);
    redk_kernel<1><<<(32 * 4096 + 255) / 256, blk, 0, stream>>>(part, cb3, nullptr, t3b, 32, 4096, 8);
    gemm_k<EPI_PART, 0><<<dim3(31, 1, 8), blk, 0, stream>>>(t3b, c4T, nullptr, nullptr, part,
            nullptr, nullptr, nullptr, 32, NCLS, 4096, 4096, 4096, 512);
    redk_kernel<0><<<(32 * NCLS + 255) / 256, blk, 0, stream>>>(part, cb4, outv, nullptr, 32, NCLS, 8);
}

// Round 6
// 2394.602 us; speedup vs baseline: 1.8171x; 1.0983x over previous
//
#include <hip/hip_runtime.h>
#include <stdint.h>

#define NTOK 9600
#define TT   300
#define DD   1024
#define HH   8
#define DFF  4096
#define FIN  1152
#define DATT 128
#define NCLS 3862
#define TP   320   // kv padded for PV k-steps
#define NQT  19    // ceil(304/16) tiles of 16

typedef unsigned short u16;
typedef __attribute__((ext_vector_type(8))) short short8;
typedef __attribute__((ext_vector_type(4))) float f32x4;

__device__ __forceinline__ int imin(int a, int b){ return a < b ? a : b; }

__device__ __forceinline__ u16 f2bf(float f){
    union { float f; uint32_t u; } v; v.f = f;
    uint32_t u = v.u;
    return (u16)((u + 0x7fffu + ((u >> 16) & 1u)) >> 16);
}

__device__ __forceinline__ f32x4 mfma16(short8 a, short8 b, f32x4 c){
    return __builtin_amdgcn_mfma_f32_16x16x32_bf16(a, b, c, 0, 0, 0);
}

// async global->LDS, 16B per lane. LDS dest must be wave-uniform base + lane*16 (linear).
__device__ __forceinline__ void gll16(const void* g, void* l){
    __builtin_amdgcn_global_load_lds((const __attribute__((address_space(1))) void*)g,
                                     (__attribute__((address_space(3))) void*)l, 16, 0, 0);
}

// ---------------- PE table ----------------
__global__ void __launch_bounds__(256) pe_kernel(float* __restrict__ pe)
{
    const int i = blockIdx.x * 256 + threadIdx.x;
    if (i >= TT * DD) return;
    const int t = i >> 10, d = i & 1023;
    const float fr = expf(-(float)(d & ~1) * (9.210340371976184f / 1024.0f));
    const float ang = (float)t * fr;
    pe[i] = (d & 1) ? cosf(ang) : sinf(ang);
}

// ---------------- feats concat + /255 -> bf16 ----------------
__global__ void __launch_bounds__(256) feats_kernel(const float* __restrict__ rgb,
        const float* __restrict__ aud, u16* __restrict__ out)
{
    const long i = (long)blockIdx.x * 256 + threadIdx.x;
    if (i >= (long)NTOK * FIN) return;
    const int row = (int)(i / FIN), c = (int)(i % FIN);
    const float v = (c < 1024) ? rgb[(size_t)row * 1024 + c] : aud[(size_t)row * 128 + (c - 1024)];
    out[i] = f2bf(v * (1.0f / 255.0f));
}

// ---------------- weight transpose + convert: W[K,N] f32 -> Wt[N,K] bf16 ----------------
__global__ void __launch_bounds__(256) wconv_kernel(const float* __restrict__ W,
        u16* __restrict__ Wt, int K, int N)
{
    __shared__ float tile[32][33];
    const int k0 = blockIdx.y * 32, n0 = blockIdx.x * 32;
    const int tx = threadIdx.x, ty = threadIdx.y;   // 32 x 8
    #pragma unroll
    for (int i = 0; i < 4; ++i) {
        const int k = k0 + ty + i * 8, n = n0 + tx;
        tile[ty + i * 8][tx] = (k < K && n < N) ? W[(size_t)k * N + n] : 0.f;
    }
    __syncthreads();
    #pragma unroll
    for (int i = 0; i < 4; ++i) {
        const int n = n0 + ty + i * 8, k = k0 + tx;
        if (n < N && k < K) Wt[(size_t)n * K + k] = f2bf(tile[tx][ty + i * 8]);
    }
}

// ---------------- f32 -> bf16 ----------------
__global__ void __launch_bounds__(256) f2bf_kernel(const float* __restrict__ in,
        u16* __restrict__ out, int n)
{
    const int i = blockIdx.x * 256 + threadIdx.x;
    if (i < n) out[i] = f2bf(in[i]);
}

// ---------------- fused QKV bias gather: [4][3072] ----------------
__global__ void __launch_bounds__(256) qkvbias_kernel(const float* __restrict__ bq,
        const float* __restrict__ bk, const float* __restrict__ bv, float* __restrict__ out)
{
    const int i = blockIdx.x * 256 + threadIdx.x;
    if (i >= 4 * 3072) return;
    const int l = i / 3072, c = i % 3072;
    float v;
    if      (c < 1024) v = bq[l * 1024 + c];
    else if (c < 2048) v = bk[l * 1024 + c - 1024];
    else               v = bv[l * 1024 + c - 2048];
    out[i] = v;
}

// ---------------- LayerNorm (ddof=1, a*(x-m)/(std+eps)+b) ----------------
template<int WF>
__global__ void __launch_bounds__(256) ln_kernel(const float* __restrict__ xin,
        const float* __restrict__ ga, const float* __restrict__ gb,
        u16* __restrict__ ob, float* of)
{
    const int row = blockIdx.x, t = threadIdx.x;
    const float4 xv = *(const float4*)(xin + (size_t)row * 1024 + t * 4);
    float s1 = xv.x + xv.y + xv.z + xv.w;
    float s2 = xv.x * xv.x + xv.y * xv.y + xv.z * xv.z + xv.w * xv.w;
    #pragma unroll
    for (int o = 1; o < 64; o <<= 1) { s1 += __shfl_xor(s1, o); s2 += __shfl_xor(s2, o); }
    __shared__ float r1[4], r2[4];
    const int lane = t & 63, wid = t >> 6;
    if (lane == 0) { r1[wid] = s1; r2[wid] = s2; }
    __syncthreads();
    s1 = r1[0] + r1[1] + r1[2] + r1[3];
    s2 = r2[0] + r2[1] + r2[2] + r2[3];
    const float mean = s1 * (1.0f / 1024.0f);
    const float var  = (s2 - 1024.0f * mean * mean) * (1.0f / 1023.0f);
    const float inv  = 1.0f / (sqrtf(fmaxf(var, 0.f)) + 1e-6f);
    const float4 av  = *(const float4*)(ga + t * 4);
    const float4 bv  = *(const float4*)(gb + t * 4);
    const float y0 = av.x * (xv.x - mean) * inv + bv.x;
    const float y1 = av.y * (xv.y - mean) * inv + bv.y;
    const float y2 = av.z * (xv.z - mean) * inv + bv.z;
    const float y3 = av.w * (xv.w - mean) * inv + bv.w;
    ushort4 o4; o4.x = f2bf(y0); o4.y = f2bf(y1); o4.z = f2bf(y2); o4.w = f2bf(y3);
    *(ushort4*)(ob + (size_t)row * 1024 + t * 4) = o4;
    if (WF) {
        float4 yo; yo.x = y0; yo.y = y1; yo.z = y2; yo.w = y3;
        *(float4*)(of + (size_t)row * 1024 + t * 4) = yo;
    }
}

// ---------------- epilogue codes ----------------
#define EPI_EMBED        0
#define EPI_QKV          1   // route col>>10 to outB/outB2/outB3 (stride 1024)
#define EPI_B_RELU_BF16  2
#define EPI_B_RES_F32    3
#define EPI_B_TANH_F32   4
#define EPI_ACC_F32      5   // outF = v + extra (no bias; FFN2 second half)
#define EPI_PART         6   // partials for split-K: outF[z*M*N + oi] = v

// ---- generic bf16 MFMA GEMM: C = A[M,K] * Bt[N,K]^T (128x128, 2-phase dbuf, proven) ----
template<int EPI, int SWZ>
__global__ void __launch_bounds__(256) gemm_k(const u16* __restrict__ A, const u16* __restrict__ Bt,
        const float* __restrict__ bias, const float* extra,
        float* outF, u16* outB, u16* outB2, u16* outB3, int M, int N, int K,
        int lda, int ldb, int kchunk)
{
    __shared__ __align__(16) u16 As[2][4096];
    __shared__ __align__(16) u16 Bs[2][4096];
    const int tid = threadIdx.x;
    int bm, bn;
    if (SWZ) {
        int lin = blockIdx.y * gridDim.x + blockIdx.x;
        const int nwg = gridDim.x * gridDim.y;
        const int cpx = nwg >> 3;
        lin = (lin & 7) * cpx + (lin >> 3);
        bm = lin / gridDim.x;
        bn = lin - bm * gridDim.x;
    } else {
        bm = blockIdx.y; bn = blockIdx.x;
    }
    const int lane = tid & 63, wid = tid >> 6;
    const int lg = lane >> 4, lr = lane & 15;
    const int wr = wid >> 1, wc = wid & 1;

    int koff = 0, Keff = K;
    if (kchunk > 0) { koff = blockIdx.z * kchunk; Keff = kchunk; }

    const int srow = tid >> 2;
    const int skc  = (tid & 3) * 8;
    const u16* ap0 = A  + (size_t)imin(bm * 128 + srow,      M - 1) * lda + skc + koff;
    const u16* ap1 = A  + (size_t)imin(bm * 128 + srow + 64, M - 1) * lda + skc + koff;
    const u16* bp0 = Bt + (size_t)imin(bn * 128 + srow,      N - 1) * ldb + skc + koff;
    const u16* bp1 = Bt + (size_t)imin(bn * 128 + srow + 64, N - 1) * ldb + skc + koff;

    f32x4 acc[4][4] = {};

    auto STAGE = [&](int b, int k0) {
        gll16(ap0 + k0, &As[b][tid * 8]);
        gll16(ap1 + k0, &As[b][2048 + tid * 8]);
        gll16(bp0 + k0, &Bs[b][tid * 8]);
        gll16(bp1 + k0, &Bs[b][2048 + tid * 8]);
    };
    auto COMPUTE = [&](int b) {
        short8 af[4], bf[4];
        #pragma unroll
        for (int m = 0; m < 4; ++m)
            af[m] = *(const short8*)(&As[b][(wr * 64 + m * 16 + lr) * 32 + lg * 8]);
        #pragma unroll
        for (int n = 0; n < 4; ++n)
            bf[n] = *(const short8*)(&Bs[b][(wc * 64 + n * 16 + lr) * 32 + lg * 8]);
        #pragma unroll
        for (int m = 0; m < 4; ++m)
            #pragma unroll
            for (int n = 0; n < 4; ++n)
                acc[m][n] = mfma16(af[m], bf[n], acc[m][n]);
    };

    STAGE(0, 0);
    __syncthreads();
    int cur = 0;
    for (int k0 = 32; k0 < Keff; k0 += 32) {
        STAGE(cur ^ 1, k0);
        COMPUTE(cur);
        __syncthreads();
        cur ^= 1;
    }
    COMPUTE(cur);

    #pragma unroll
    for (int m = 0; m < 4; ++m) {
        const int rb = bm * 128 + wr * 64 + m * 16 + lg * 4;
        #pragma unroll
        for (int n = 0; n < 4; ++n) {
            const int col = bn * 128 + wc * 64 + n * 16 + lr;
            if (col >= N) continue;
            const float bvl = (EPI == EPI_PART || EPI == EPI_ACC_F32) ? 0.f : bias[col];
            #pragma unroll
            for (int j = 0; j < 4; ++j) {
                const int r = rb + j;
                if (r >= M) continue;
                const float v = acc[m][n][j];
                const size_t oi = (size_t)r * N + col;
                if      (EPI == EPI_EMBED)       outF[oi] = (v + bvl) * 32.0f + extra[(size_t)(r % 300) * 1024 + col];
                else if (EPI == EPI_QKV) {
                    const int q = col >> 10, lc = col & 1023;
                    u16* dst = (q == 0) ? outB : ((q == 1) ? outB2 : outB3);
                    dst[(size_t)r * 1024 + lc] = f2bf(v + bvl);
                }
                else if (EPI == EPI_B_RELU_BF16) outB[oi] = f2bf(fmaxf(v + bvl, 0.f));
                else if (EPI == EPI_B_RES_F32)   outF[oi] = v + bvl + extra[oi];
                else if (EPI == EPI_B_TANH_F32)  outF[oi] = tanhf(v + bvl);
                else if (EPI == EPI_ACC_F32)     outF[oi] = v + extra[oi];
                else if (EPI == EPI_PART)        outF[(size_t)blockIdx.z * M * N + oi] = v;
            }
        }
    }
}

// ==== 256x256 BK=32 ring-2 counted-vmcnt GEMM (T3/T4/T5/T2), 512 threads, 8 waves 2x4 ====
// Requires: M arbitrary (A-row clamped), N % 256 == 0, K % 32 == 0, K/32 >= 4. 1-D grid.
// LDS swizzle involution: physical kgrp = logical kgrp ^ ((row>>1)&3)  (within 32-k tile).
template<int EPI>
__global__ void __launch_bounds__(512, 2) gemm_big(const u16* __restrict__ A, const u16* __restrict__ Bt,
        const float* __restrict__ bias, float* outF, u16* outB, u16* outB2, u16* outB3,
        int M, int N, int K, int lda, int ldb)
{
    __shared__ __align__(16) u16 LA[2][256 * 32];   // 16 KB x2
    __shared__ __align__(16) u16 LB[2][256 * 32];   // 16 KB x2  (total 64 KB)
    const int tid = threadIdx.x;
    int lin = blockIdx.x;
    const int nwg = gridDim.x;
    if ((nwg & 7) == 0) { const int cpx = nwg >> 3; lin = (lin & 7) * cpx + (lin >> 3); }
    const int ntN = N >> 8;
    const int bm = lin / ntN, bn = lin - (lin / ntN) * ntN;

    const int lane = tid & 63, wid = tid >> 6;
    const int wm = wid >> 2, wn = wid & 3;          // 2 x 4 waves
    const int lg = lane >> 4, lr = lane & 15;

    // staging: thread tid covers physical row tid>>2, phys kgrp tid&3; source kgrp pre-swizzled.
    const int prow = tid >> 2;
    const int skg  = (((tid & 3) ^ ((tid >> 3) & 3)) * 8);
    const u16* asrc0 = A  + (size_t)imin(bm * 256 + prow,       M - 1) * lda + skg;
    const u16* asrc1 = A  + (size_t)imin(bm * 256 + prow + 128, M - 1) * lda + skg;
    const u16* bsrc0 = Bt + (size_t)(bn * 256 + prow)       * ldb + skg;
    const u16* bsrc1 = Bt + (size_t)(bn * 256 + prow + 128) * ldb + skg;

    auto STAGE = [&](int s, int k0) {               // 4 per-wave loads, 1 KB each
        gll16(asrc0 + k0, &LA[s][tid * 8]);
        gll16(asrc1 + k0, &LA[s][4096 + tid * 8]);
        gll16(bsrc0 + k0, &LB[s][tid * 8]);
        gll16(bsrc1 + k0, &LB[s][4096 + tid * 8]);
    };

    // fragment LDS offsets (u16 units), swizzled read: kgrp_eff = lg ^ ((lr>>1)&3)
    const int kge = (lg ^ ((lr >> 1) & 3)) * 8;
    int aoff[8], boff[4];
    #pragma unroll
    for (int m = 0; m < 8; ++m) aoff[m] = (wm * 128 + m * 16 + lr) * 32 + kge;
    #pragma unroll
    for (int n = 0; n < 4; ++n) boff[n] = (wn * 64 + n * 16 + lr) * 32 + kge;

    f32x4 acc[8][4] = {};
    short8 af[8], bf[4];

    const int nk = K >> 5;
    STAGE(0, 0);
    STAGE(1, 32);
    asm volatile("s_waitcnt vmcnt(4)" ::: "memory");   // tile0 landed (own slice; collective via barrier)
    asm volatile("s_barrier" ::: "memory");
    __builtin_amdgcn_sched_barrier(0);

    auto BODY = [&](int t, int s, bool doStage) {
        // ---- phase A: read all fragments of tile t, compute m=0..3 ----
        #pragma unroll
        for (int m = 0; m < 8; ++m) af[m] = *(const short8*)(&LA[s][aoff[m]]);
        #pragma unroll
        for (int n = 0; n < 4; ++n) bf[n] = *(const short8*)(&LB[s][boff[n]]);
        asm volatile("s_waitcnt lgkmcnt(0)" ::: "memory");   // ALL my reads retired (incl. m=4..7)
        __builtin_amdgcn_sched_barrier(0);
        __builtin_amdgcn_s_setprio(1);
        #pragma unroll
        for (int m = 0; m < 4; ++m)
            #pragma unroll
            for (int n = 0; n < 4; ++n)
                acc[m][n] = mfma16(af[m], bf[n], acc[m][n]);
        __builtin_amdgcn_s_setprio(0);
        asm volatile("s_barrier" ::: "memory");              // seals ALL waves' reads of slot s
        __builtin_amdgcn_sched_barrier(0);
        // ---- phase B: prefetch tile t+2 into slot s (just sealed), compute m=4..7 ----
        if (doStage) STAGE(s, (t + 2) * 32);
        __builtin_amdgcn_s_setprio(1);
        #pragma unroll
        for (int m = 4; m < 8; ++m)
            #pragma unroll
            for (int n = 0; n < 4; ++n)
                acc[m][n] = mfma16(af[m], bf[n], acc[m][n]);
        __builtin_amdgcn_s_setprio(0);
    };

    for (int t = 0; t < nk - 2; ++t) {
        BODY(t, t & 1, true);
        asm volatile("s_waitcnt vmcnt(4)" ::: "memory");     // tile t+1 landed; t+2 stays in flight
        __builtin_amdgcn_sched_barrier(0);
        asm volatile("s_barrier" ::: "memory");
        __builtin_amdgcn_sched_barrier(0);
    }
    BODY(nk - 2, (nk - 2) & 1, false);
    asm volatile("s_waitcnt vmcnt(0)" ::: "memory");         // last tile landed
    __builtin_amdgcn_sched_barrier(0);
    asm volatile("s_barrier" ::: "memory");
    __builtin_amdgcn_sched_barrier(0);
    BODY(nk - 1, (nk - 1) & 1, false);

    // ---- epilogue ----
    #pragma unroll
    for (int m = 0; m < 8; ++m) {
        const int rb = bm * 256 + wm * 128 + m * 16 + lg * 4;
        #pragma unroll
        for (int n = 0; n < 4; ++n) {
            const int col = bn * 256 + wn * 64 + n * 16 + lr;
            const float bvl = bias[col];
            #pragma unroll
            for (int j = 0; j < 4; ++j) {
                const int r = rb + j;
                if (r >= M) continue;
                const float v = acc[m][n][j] + bvl;
                if (EPI == EPI_QKV) {
                    const int q = col >> 10, lc = col & 1023;
                    u16* dst = (q == 0) ? outB : ((q == 1) ? outB2 : outB3);
                    dst[(size_t)r * 1024 + lc] = f2bf(v);
                } else {  // EPI_B_RELU_BF16
                    outB[(size_t)r * N + col] = f2bf(fmaxf(v, 0.f));
                }
            }
        }
    }
}

// ---------------- split-K reduce + bias (+tanh) ----------------
template<int TANH>
__global__ void __launch_bounds__(256) redk_kernel(const float* __restrict__ part,
        const float* __restrict__ bias, float* outF, u16* outB, int M, int N, int Z)
{
    const int i = blockIdx.x * 256 + threadIdx.x;
    if (i >= M * N) return;
    const int col = i % N;
    float s = 0.f;
    for (int z = 0; z < Z; ++z) s += part[(size_t)z * M * N + i];
    s += bias[col];
    if (TANH) outB[i] = f2bf(tanhf(s));
    else      outF[i] = s;
}

// ---------------- attention: scores + softmax -> P bf16 ----------------
__global__ void __launch_bounds__(256) attn_scores_kernel(const u16* __restrict__ Qb,
        const u16* __restrict__ Kb, u16* __restrict__ P)
{
    __shared__ __align__(16) u16 Ks[304 * 128];   // 77824 B, XOR-swizzled rows
    const int bh = blockIdx.x, b = bh >> 3, h = bh & 7;
    const int tid = threadIdx.x, lane = tid & 63, wid = tid >> 6;
    const int lg = lane >> 4, lr = lane & 15;

    for (int c = tid; c < 304 * 16; c += 256) {
        const int kv = c >> 4, part = c & 15;
        const int tok = b * 300 + imin(kv, 299);
        const short8 v = *(const short8*)(Kb + (size_t)tok * 1024 + h * 128 + part * 8);
        int byte_ = kv * 256 + part * 16;
        byte_ ^= (kv & 7) << 4;
        *(short8*)((char*)Ks + byte_) = v;
    }
    __syncthreads();

    const float scale = 0.08838834764831845f;   // 1/sqrt(128)
    for (int qt = wid; qt < NQT; qt += 4) {
        f32x4 acc[NQT] = {};
        const int qtok = b * 300 + imin(qt * 16 + lr, 299);
        const u16* qrow = Qb + (size_t)qtok * 1024 + h * 128;
        #pragma unroll
        for (int kk = 0; kk < 4; ++kk) {
            const short8 aq = *(const short8*)(qrow + kk * 32 + lg * 8);
            #pragma unroll
            for (int nt = 0; nt < NQT; ++nt) {
                const int kvrow = nt * 16 + lr;
                int byte_ = kvrow * 256 + kk * 64 + lg * 16;
                byte_ ^= (kvrow & 7) << 4;
                const short8 bk = *(const short8*)((char*)Ks + byte_);
                acc[nt] = mfma16(aq, bk, acc[nt]);
            }
        }
        #pragma unroll
        for (int j = 0; j < 4; ++j) {
            float vals[NQT];
            float m = -1e30f;
            #pragma unroll
            for (int nt = 0; nt < NQT; ++nt) {
                float s = acc[nt][j] * scale;
                if (nt * 16 + lr >= 300) s = -1e30f;
                vals[nt] = s;
                m = fmaxf(m, s);
            }
            #pragma unroll
            for (int o = 1; o < 16; o <<= 1) m = fmaxf(m, __shfl_xor(m, o));
            float sum = 0.f;
            #pragma unroll
            for (int nt = 0; nt < NQT; ++nt) { const float e = __expf(vals[nt] - m); vals[nt] = e; sum += e; }
            #pragma unroll
            for (int o = 1; o < 16; o <<= 1) sum += __shfl_xor(sum, o);
            const float inv = 1.0f / sum;
            const int q = qt * 16 + lg * 4 + j;
            if (q < 300) {
                u16* prow = P + ((size_t)bh * 300 + q) * TP;
                #pragma unroll
                for (int nt = 0; nt < NQT; ++nt) prow[nt * 16 + lr] = f2bf(vals[nt] * inv);
                prow[304 + lr] = 0;   // zero kv pad 304..319
            }
        }
    }
}

// ---------------- attention: O = P @ V ----------------
__global__ void __launch_bounds__(256) attn_pv_kernel(const u16* __restrict__ P,
        const u16* __restrict__ Vb, u16* __restrict__ O)
{
    __shared__ __align__(16) u16 Vs[128 * TP];   // V^T, 81920 B, XOR-swizzled rows
    const int bh = blockIdx.x, b = bh >> 3, h = bh & 7;
    const int tid = threadIdx.x, lane = tid & 63, wid = tid >> 6;
    const int lg = lane >> 4, lr = lane & 15;

    for (int c = tid; c < 304 * 16; c += 256) {
        const int kv = c >> 4, dp = c & 15;
        const int tok = b * 300 + imin(kv, 299);
        const short8 v = *(const short8*)(Vb + (size_t)tok * 1024 + h * 128 + dp * 8);
        #pragma unroll
        for (int jj = 0; jj < 8; ++jj) {
            const int d = dp * 8 + jj;
            int byte_ = d * (TP * 2) + kv * 2;
            byte_ ^= (d & 7) << 4;
            *(u16*)((char*)Vs + byte_) = (u16)v[jj];
        }
    }
    for (int c = tid; c < 128 * 16; c += 256) {     // zero kv pad 304..319
        const int d = c >> 4, kv = 304 + (c & 15);
        int byte_ = d * (TP * 2) + kv * 2;
        byte_ ^= (d & 7) << 4;
        *(u16*)((char*)Vs + byte_) = 0;
    }
    __syncthreads();

    for (int qt = wid; qt < NQT; qt += 4) {
        f32x4 acc[8] = {};
        const int q = imin(qt * 16 + lr, 299);
        const u16* prow = P + ((size_t)bh * 300 + q) * TP;
        #pragma unroll
        for (int kk = 0; kk < 10; ++kk) {
            const short8 ap = *(const short8*)(prow + kk * 32 + lg * 8);
            #pragma unroll
            for (int nt = 0; nt < 8; ++nt) {
                const int d = nt * 16 + lr;
                int byte_ = d * (TP * 2) + kk * 64 + lg * 16;
                byte_ ^= (d & 7) << 4;
                const short8 bv8 = *(const short8*)((char*)Vs + byte_);
                acc[nt] = mfma16(ap, bv8, acc[nt]);
            }
        }
        #pragma unroll
        for (int nt = 0; nt < 8; ++nt) {
            #pragma unroll
            for (int j = 0; j < 4; ++j) {
                const int qq = qt * 16 + lg * 4 + j;
                if (qq < 300)
                    O[((size_t)(b * 300 + qq)) * 1024 + h * 128 + nt * 16 + lr] = f2bf(acc[nt][j]);
            }
        }
    }
}

// ---------------- classifier tail ----------------
__global__ void __launch_bounds__(256) logits_kernel(const float* __restrict__ a1,
        const float* __restrict__ cw2, const float* __restrict__ cb2, float* __restrict__ out)
{
    const int tok = blockIdx.x * 4 + (threadIdx.x >> 6);
    const int lane = threadIdx.x & 63;
    if (tok >= NTOK) return;
    const float v0 = a1[(size_t)tok * 128 + lane];
    const float v1 = a1[(size_t)tok * 128 + 64 + lane];
    #pragma unroll
    for (int hp = 0; hp < 4; ++hp) {
        float s = v0 * cw2[lane * 4 + hp] + v1 * cw2[(64 + lane) * 4 + hp];
        #pragma unroll
        for (int o = 1; o < 64; o <<= 1) s += __shfl_xor(s, o);
        if (lane == 0) out[(size_t)tok * 4 + hp] = s + cb2[hp];
    }
}

__global__ void __launch_bounds__(512) softmaxT_kernel(const float* __restrict__ lgt,
        float* __restrict__ alpha, float* __restrict__ outAlpha)
{
    const int bh = blockIdx.x;           // b*4 + hop
    const int b = bh >> 2, hp = bh & 3;
    const int t = threadIdx.x;
    const float v = (t < 300) ? lgt[((size_t)(b * 300 + t)) * 4 + hp] : -1e30f;
    float m = v;
    #pragma unroll
    for (int o = 1; o < 64; o <<= 1) m = fmaxf(m, __shfl_xor(m, o));
    __shared__ float rm[8], rs[8];
    const int lane = t & 63, wid = t >> 6;
    if (lane == 0) rm[wid] = m;
    __syncthreads();
    m = rm[0];
    #pragma unroll
    for (int i = 1; i < 8; ++i) m = fmaxf(m, rm[i]);
    const float e = (t < 300) ? __expf(v - m) : 0.f;
    float s = e;
    #pragma unroll
    for (int o = 1; o < 64; o <<= 1) s += __shfl_xor(s, o);
    if (lane == 0) rs[wid] = s;
    __syncthreads();
    s = rs[0] + rs[1] + rs[2] + rs[3] + rs[4] + rs[5] + rs[6] + rs[7];
    if (t < 300) {
        const float a = e / s;
        alpha[(size_t)bh * 300 + t] = a;
        outAlpha[(size_t)bh * 300 + t] = a;
    }
}

__global__ void __launch_bounds__(256) pool_kernel(const float* __restrict__ alpha,
        const float* __restrict__ xln, float* __restrict__ wsp)
{
    const int bh = blockIdx.x, b = bh >> 2;
    const int d = blockIdx.y * 256 + threadIdx.x;
    const float* xp = xln + (size_t)b * 300 * 1024 + d;
    const float* al = alpha + (size_t)bh * 300;
    float acc = 0.f;
    for (int t = 0; t < 300; ++t) acc += al[t] * xp[(size_t)t * 1024];
    wsp[(size_t)bh * 1024 + d] = acc;
}

// =====================================================================
extern "C" void kernel_launch(void* const* d_in, const int* in_sizes, int n_in,
                              void* d_out, int out_size, void* d_ws, size_t ws_size,
                              hipStream_t stream)
{
    const float* rgb     = (const float*)d_in[0];
    const float* aud     = (const float*)d_in[1];
    const float* embed_W = (const float*)d_in[2];
    const float* embed_b = (const float*)d_in[3];
    const float* Wq      = (const float*)d_in[4];
    const float* bq      = (const float*)d_in[5];
    const float* Wk      = (const float*)d_in[6];
    const float* bk      = (const float*)d_in[7];
    const float* Wv      = (const float*)d_in[8];
    const float* bv      = (const float*)d_in[9];
    const float* Wo      = (const float*)d_in[10];
    const float* bo      = (const float*)d_in[11];
    const float* ln1_a   = (const float*)d_in[12];
    const float* ln1_b   = (const float*)d_in[13];
    const float* W1f     = (const float*)d_in[14];
    const float* b1f     = (const float*)d_in[15];
    const float* W2f     = (const float*)d_in[16];
    const float* b2f     = (const float*)d_in[17];
    const float* ln2_a   = (const float*)d_in[18];
    const float* ln2_b   = (const float*)d_in[19];
    const float* fn_a    = (const float*)d_in[20];
    const float* fn_b    = (const float*)d_in[21];
    const float* cw1     = (const float*)d_in[22];
    const float* cb1     = (const float*)d_in[23];
    const float* cw2     = (const float*)d_in[24];
    const float* cb2     = (const float*)d_in[25];
    const float* cw3     = (const float*)d_in[26];
    const float* cb3     = (const float*)d_in[27];
    const float* cw4     = (const float*)d_in[28];
    const float* cb4     = (const float*)d_in[29];

    const bool bigS = ws_size >= ((size_t)238 << 20);   // host-side constant per process
    const size_t Ssz = bigS ? (size_t)NTOK * DFF * 2 : (size_t)256 * 300 * TP * 2;

    char* base = (char*)d_ws;
    size_t off = 0;
    auto alloc = [&](size_t bytes) -> char* {
        char* p = base + off; off += (bytes + 255) & ~(size_t)255; return p; };

    float* x    = (float*)alloc((size_t)NTOK * DD * 4);        // 39.3 MB (c3T aliases after final LN)
    float* pe   = (float*)alloc((size_t)TT * DD * 4);          //  1.2 MB
    u16*  hbuf  = (u16*) alloc((size_t)NTOK * DD * 2);         // 19.7 MB (Ob, splitK partials alias)
    u16*  Qb    = (u16*) alloc((size_t)NTOK * DD * 2);         // 19.7 MB  \ xln aliases Qb+Kb
    u16*  Kb    = (u16*) alloc((size_t)NTOK * DD * 2);         // 19.7 MB  /
    u16*  Vb    = (u16*) alloc((size_t)NTOK * DD * 2);         // 19.7 MB (xlnb aliases)
    u16*  S     = (u16*) alloc(Ssz);                           // 49.2 or 78.6 MB shared region
    float* lgts = (float*)alloc((size_t)NTOK * 4 * 4);
    float* alph = (float*)alloc((size_t)128 * 300 * 4);
    float* wsp  = (float*)alloc((size_t)32 * 4096 * 4);
    u16*  wsb   = (u16*) alloc((size_t)32 * 4096 * 2);
    u16*  t3b   = (u16*) alloc((size_t)32 * 4096 * 2);
    float* bqkv = (float*)alloc((size_t)4 * 3072 * 4);         // fused QKV bias
    u16*  eWt   = (u16*) alloc((size_t)1024 * 1152 * 2);       //  2.4 MB
    u16*  WqkvT = (u16*) alloc((size_t)3 * 1024 * 1024 * 2);   //  6.3 MB (fused, per-layer reuse)
    u16*  WoT   = (u16*) alloc((size_t)1024 * 1024 * 2);
    u16*  W1T   = (u16*) alloc((size_t)DFF * DD * 2);          //  8.4 MB [DFF rows, DD]
    u16*  W2T   = (u16*) alloc((size_t)DD * DFF * 2);          //  8.4 MB [DD rows, DFF]
    u16*  c1T   = (u16*) alloc((size_t)128 * 1024 * 2);
    if (off > ws_size) return;   // loud failure if insufficient

    u16*  featsb = S;             // 22.1 MB, dead after embed GEMM
    u16*  pbuf   = S;             // 49.2 MB, attn P for all 256 bh (dead outside attn)
    u16*  midc   = S;             // FFN activation (full DFF if bigS, else half)
    u16*  Ob     = hbuf;          // attention output (hbuf dead after QKV gemm)
    float* xln   = (float*)Qb;    // final-LN f32 output: spans Qb+Kb (both dead)
    u16*  xlnb   = Vb;            // final-LN bf16 output (Vb dead)
    float* a1    = (float*)S;     // 4.9 MB, classifier phase
    u16*  c3T    = (u16*)x;       // 32.0 MB  <= 39.3 (x dead after final LN)
    u16*  c4T    = S;             // 31.6 MB  (written after logits; a1 dead)
    float* part  = (float*)hbuf;  // split-K partials, <=4.1 MB (hbuf dead in classifier)
    float* outv     = (float*)d_out;
    float* outAlpha = outv + (size_t)32 * NCLS;

    const dim3 blk(256);

    pe_kernel<<<(TT * DD + 255) / 256, blk, 0, stream>>>(pe);
    feats_kernel<<<(int)(((size_t)NTOK * FIN + 255) / 256), blk, 0, stream>>>(rgb, aud, featsb);
    qkvbias_kernel<<<(4 * 3072 + 255) / 256, blk, 0, stream>>>(bq, bk, bv, bqkv);

    auto wconv = [&](const float* W, u16* Wt, int K, int N) {
        dim3 g((N + 31) / 32, (K + 31) / 32);
        wconv_kernel<<<g, dim3(32, 8), 0, stream>>>(W, Wt, K, N);
    };
    wconv(embed_W, eWt, FIN, DD);
    wconv(cw1, c1T, DD, DATT);

    // embed: x = (feats @ W + b)*sqrt(D) + PE   (grid 600 % 8 == 0 -> SWZ)
    gemm_k<EPI_EMBED, 1><<<dim3(8, 75), blk, 0, stream>>>(featsb, eWt, embed_b, pe, x,
            nullptr, nullptr, nullptr, NTOK, DD, FIN, FIN, FIN, 0);

    for (int i = 0; i < 4; ++i) {
        wconv(Wq  + (size_t)i * DD * DD,  WqkvT,                 DD, DD);
        wconv(Wk  + (size_t)i * DD * DD,  WqkvT + 1024 * 1024,   DD, DD);
        wconv(Wv  + (size_t)i * DD * DD,  WqkvT + 2 * 1024 * 1024, DD, DD);
        wconv(Wo  + (size_t)i * DD * DD,  WoT, DD, DD);
        wconv(W1f + (size_t)i * DD * DFF, W1T, DD, DFF);
        wconv(W2f + (size_t)i * DFF * DD, W2T, DFF, DD);

        ln_kernel<0><<<NTOK, blk, 0, stream>>>(x, ln1_a + (size_t)i * DD, ln1_b + (size_t)i * DD, hbuf, nullptr);
        // fused QKV: 256^2 tile kernel, grid 38*12 = 456 (%8==0 -> swizzle)
        gemm_big<EPI_QKV><<<456, dim3(512), 0, stream>>>(hbuf, WqkvT, bqkv + (size_t)i * 3072,
                nullptr, Qb, Kb, Vb, NTOK, 3072, DD, DD, DD);
        attn_scores_kernel<<<256, blk, 0, stream>>>(Qb, Kb, pbuf);
        attn_pv_kernel<<<256, blk, 0, stream>>>(pbuf, Vb, Ob);      // Ob = hbuf (dead now)
        gemm_k<EPI_B_RES_F32, 1><<<dim3(8, 75), blk, 0, stream>>>(Ob, WoT, bo + (size_t)i * DD, x, x,
                nullptr, nullptr, nullptr, NTOK, DD, DD, DD, DD, 0);
        ln_kernel<0><<<NTOK, blk, 0, stream>>>(x, ln2_a + (size_t)i * DD, ln2_b + (size_t)i * DD, hbuf, nullptr);
        if (bigS) {
            // FFN1 unsplit: grid 38*16 = 608 (%8==0); midc [9600][4096]
            gemm_big<EPI_B_RELU_BF16><<<608, dim3(512), 0, stream>>>(hbuf, W1T, b1f + (size_t)i * DFF,
                    nullptr, midc, nullptr, nullptr, NTOK, DFF, DD, DD, DD);
            gemm_k<EPI_B_RES_F32, 1><<<dim3(8, 75), blk, 0, stream>>>(midc, W2T, b2f + (size_t)i * DD,
                    x, x, nullptr, nullptr, nullptr, NTOK, DD, DFF, DFF, DFF, 0);
        } else {
            for (int h = 0; h < 2; ++h) {
                gemm_big<EPI_B_RELU_BF16><<<304, dim3(512), 0, stream>>>(hbuf, W1T + (size_t)h * 2048 * DD,
                        b1f + (size_t)i * DFF + h * 2048, nullptr, midc, nullptr, nullptr,
                        NTOK, 2048, DD, DD, DD);
                if (h == 0)
                    gemm_k<EPI_B_RES_F32, 1><<<dim3(8, 75), blk, 0, stream>>>(midc, W2T + (size_t)h * 2048,
                            b2f + (size_t)i * DD, x, x, nullptr, nullptr, nullptr, NTOK, DD, 2048, 2048, DFF, 0);
                else
                    gemm_k<EPI_ACC_F32, 1><<<dim3(8, 75), blk, 0, stream>>>(midc, W2T + (size_t)h * 2048,
                            b2f + (size_t)i * DD, x, x, nullptr, nullptr, nullptr, NTOK, DD, 2048, 2048, DFF, 0);
            }
        }
    }

    ln_kernel<1><<<NTOK, blk, 0, stream>>>(x, fn_a, fn_b, xlnb, xln);
    wconv(cw3, c3T, 4096, DFF);                               // x dead -> c3T
    gemm_k<EPI_B_TANH_F32, 0><<<dim3(1, 75), blk, 0, stream>>>(xlnb, c1T, cb1, nullptr, a1,
            nullptr, nullptr, nullptr, NTOK, DATT, DD, DD, DD, 0);
    logits_kernel<<<2400, blk, 0, stream>>>(a1, cw2, cb2, lgts);
    wconv(cw4, c4T, DFF, NCLS);                               // a1 dead -> c4T
    softmaxT_kernel<<<128, dim3(512), 0, stream>>>(lgts, alph, outAlpha);
    pool_kernel<<<dim3(128, 4), blk, 0, stream>>>(alph, xln, wsp);
    f2bf_kernel<<<(32 * 4096 + 255) / 256, blk, 0, stream>>>(wsp, wsb, 32 * 4096);

    // classifier GEMMs: split-K (Z=8, Kc=512), deterministic reduce
    gemm_k<EPI_PART, 0><<<dim3(32, 1, 8), blk, 0, stream>>>(wsb, c3T, nullptr, nullptr, part,
            nullptr, nullptr, nullptr, 32, 4096, 4096, 4096, 4096, 512);
    redk_kernel<1><<<(32 * 4096 + 255) / 256, blk, 0, stream>>>(part, cb3, nullptr, t3b, 32, 4096, 8);
    gemm_k<EPI_PART, 0><<<dim3(31, 1, 8), blk, 0, stream>>>(t3b, c4T, nullptr, nullptr, part,
            nullptr, nullptr, nullptr, 32, NCLS, 4096, 4096, 4096, 512);
    redk_kernel<0><<<(32 * NCLS + 255) / 256, blk, 0, stream>>>(part, cb4, outv, nullptr, 32, NCLS, 8);
}